// Round 14
// baseline (756.186 us; speedup 1.0000x reference)
//
#include <hip/hip_runtime.h>

#define EPS_BN 1e-5f

typedef __attribute__((ext_vector_type(8))) short short8;
typedef __attribute__((ext_vector_type(4))) float f32x4;

__device__ __forceinline__ float fast_rcp(float x) { return __builtin_amdgcn_rcpf(x); }
__device__ __forceinline__ float sigmoid_f(float x) { return fast_rcp(1.0f + __expf(-x)); }
// robust tanh: no inf/inf NaN at large |x|
__device__ __forceinline__ float tanh_f(float x) { return 1.0f - 2.0f * fast_rcp(__expf(2.0f * x) + 1.0f); }

// round-to-nearest-even fp32 -> bf16 bits
__device__ __forceinline__ unsigned short f2bf(float f) {
    unsigned u = __float_as_uint(f);
    u += 0x7FFFu + ((u >> 16) & 1u);
    return (unsigned short)(u >> 16);
}
__device__ __forceinline__ unsigned pk_bf(float a, float b) {
    return (unsigned)f2bf(a) | ((unsigned)f2bf(b) << 16);
}
// value of the bf16 rounding (hi part); residual = f - bf_hi(f)
__device__ __forceinline__ float bf_hi(float f) {
    return __uint_as_float((unsigned)f2bf(f) << 16);
}
__device__ __forceinline__ float bf2f(unsigned short u) {
    return __uint_as_float((unsigned)u << 16);
}

union AFrag { short e[8]; short8 v; };
union BFrag { uint4 u; short8 v; };

// ---------------------------------------------------------------------------
// Split-precision MFMA LSTM encoder v3 (verified R13): 4 waves/block, cell-
// group distribution, in-register combine, double-buffered h_ex, 1 barrier.
// ---------------------------------------------------------------------------
__global__ __launch_bounds__(256, 2) void lstm_mfma(
    const float* __restrict__ x,      // [S, T, 2]
    const float* __restrict__ W_ih,   // [256, 2]
    const float* __restrict__ W_hh,   // [256, 64]
    const float* __restrict__ b_ih,   // [256]
    const float* __restrict__ b_hh,   // [256]
    float* __restrict__ h_out,        // [S, 64]
    float* __restrict__ c_out,        // [S, 64] or null
    int T)
{
    __shared__ unsigned h_ex[2][2][16 * 52];   // [buf][hi/lo]

    const int tid  = threadIdx.x;
    const int w    = tid >> 6;        // cell-group == wave
    const int lane = tid & 63;
    const int s    = lane & 15;       // sequence within the 16
    const int q    = lane >> 4;       // quad

    short8 ahi[4][3], alo[4][3];
#pragma unroll
    for (int gt = 0; gt < 4; ++gt) {
        const int n = gt * 64 + w * 16 + s;
#pragma unroll
        for (int kc = 0; kc < 2; ++kc) {
            const float* src = &W_hh[n * 64 + kc * 32 + q * 8];
            float4 v0 = *(const float4*)src;
            float4 v1 = *(const float4*)(src + 4);
            float v[8] = {v0.x, v0.y, v0.z, v0.w, v1.x, v1.y, v1.z, v1.w};
            AFrag a, b;
#pragma unroll
            for (int j = 0; j < 8; ++j) {
                a.e[j] = (short)f2bf(v[j]);
                b.e[j] = (short)f2bf(v[j] - bf_hi(v[j]));
            }
            ahi[gt][kc] = a.v;
            alo[gt][kc] = b.v;
        }
        AFrag a2, b2;
#pragma unroll
        for (int j = 0; j < 8; ++j) { a2.e[j] = 0; b2.e[j] = 0; }
        if (q == 0) {   // K rows 64(wi0), 65(wi1), 66(bias)
            const float wi0 = W_ih[n * 2 + 0];
            const float wi1 = W_ih[n * 2 + 1];
            const float bs  = b_ih[n] + b_hh[n];
            a2.e[0] = (short)f2bf(wi0); b2.e[0] = (short)f2bf(wi0 - bf_hi(wi0));
            a2.e[1] = (short)f2bf(wi1); b2.e[1] = (short)f2bf(wi1 - bf_hi(wi1));
            a2.e[2] = (short)f2bf(bs);  b2.e[2] = (short)f2bf(bs  - bf_hi(bs));
        }
        ahi[gt][2] = a2.v;
        alo[gt][2] = b2.v;
    }

    for (int i = tid; i < 2 * 2 * 16 * 52; i += 256) (&h_ex[0][0][0])[i] = 0u;
    __syncthreads();
    if (tid < 16) {   // s = tid
        h_ex[0][0][tid * 52 + 33] = pk_bf(1.0f, 0.0f);
        h_ex[1][0][tid * 52 + 33] = pk_bf(1.0f, 0.0f);
        float2 xv = *(const float2*)&x[((long)blockIdx.x * 16 + tid) * (long)(T * 2)];
        h_ex[0][0][tid * 52 + 32] = pk_bf(xv.x, xv.y);
        h_ex[0][1][tid * 52 + 32] = pk_bf(xv.x - bf_hi(xv.x), xv.y - bf_hi(xv.y));
    }
    __syncthreads();

    float creg[4] = {0.f, 0.f, 0.f, 0.f};

    for (int t = 0; t < T; ++t) {
        const int rb = t & 1, wb = rb ^ 1;
        BFrag bhi[3], blo[3];
#pragma unroll
        for (int kc = 0; kc < 3; ++kc) {
            const int off = s * 52 + kc * 16 + (q >> 1) * 8 + (q & 1) * 4;
            bhi[kc].u = *(const uint4*)&h_ex[rb][0][off];
            blo[kc].u = *(const uint4*)&h_ex[rb][1][off];
        }

        f32x4 acc[4];
#pragma unroll
        for (int gt = 0; gt < 4; ++gt) acc[gt] = (f32x4)0.f;

#pragma unroll
        for (int kc = 0; kc < 3; ++kc) {
            const short8 bh = bhi[kc].v;
            const short8 bl = blo[kc].v;
#pragma unroll
            for (int gt = 0; gt < 4; ++gt) {
                f32x4 a = acc[gt];
                a = __builtin_amdgcn_mfma_f32_16x16x32_bf16(ahi[gt][kc], bh, a, 0, 0, 0);
                a = __builtin_amdgcn_mfma_f32_16x16x32_bf16(ahi[gt][kc], bl, a, 0, 0, 0);
                a = __builtin_amdgcn_mfma_f32_16x16x32_bf16(alo[gt][kc], bh, a, 0, 0, 0);
                acc[gt] = a;
            }
        }

        float hval[4];
#pragma unroll
        for (int r = 0; r < 4; ++r) {
            const float c = fmaf(sigmoid_f(acc[1][r]), creg[r],
                                 sigmoid_f(acc[0][r]) * tanh_f(acc[2][r]));
            creg[r] = c;
            hval[r] = sigmoid_f(acc[3][r]) * tanh_f(c);
        }
        {
            const int w0 = s * 52 + w * 8 + q * 2;
            h_ex[wb][0][w0]     = pk_bf(hval[0], hval[1]);
            h_ex[wb][0][w0 + 1] = pk_bf(hval[2], hval[3]);
            h_ex[wb][1][w0]     = pk_bf(hval[0] - bf_hi(hval[0]), hval[1] - bf_hi(hval[1]));
            h_ex[wb][1][w0 + 1] = pk_bf(hval[2] - bf_hi(hval[2]), hval[3] - bf_hi(hval[3]));
        }
        if (tid < 16 && t + 1 < T) {
            float2 xv = *(const float2*)&x[((long)blockIdx.x * 16 + tid) * (long)(T * 2) + (t + 1) * 2];
            h_ex[wb][0][tid * 52 + 32] = pk_bf(xv.x, xv.y);
            h_ex[wb][1][tid * 52 + 32] = pk_bf(xv.x - bf_hi(xv.x), xv.y - bf_hi(xv.y));
        }
        if (t == T - 1) {
            const long seq = (long)blockIdx.x * 16 + s;
            const int j0 = w * 16 + q * 4;
            *(float4*)&h_out[seq * 64 + j0] = make_float4(hval[0], hval[1], hval[2], hval[3]);
            if (c_out)
                *(float4*)&c_out[seq * 64 + j0] = make_float4(creg[0], creg[1], creg[2], creg[3]);
        }
        __syncthreads();
    }
}

// ---------------------------------------------------------------------------
// x0[n] = concat(neigh_h[n], rel @ rW.T + rb)  -> hi/lo bf16 planes [N,128]
// ---------------------------------------------------------------------------
__global__ __launch_bounds__(256) void build_x0(
    const float* __restrict__ neigh_h, const float* __restrict__ neighbours,
    const float* __restrict__ agent_traj, const int* __restrict__ seg,
    const float* __restrict__ rW, const float* __restrict__ rb,
    unsigned short* __restrict__ x0hi, unsigned short* __restrict__ x0lo, int T)
{
    const long n = (long)blockIdx.x * 2 + (threadIdx.x >> 7);
    const int j = threadIdx.x & 127;
    float v;
    if (j < 64) {
        v = neigh_h[n*64 + j];
    } else {
        const int o = j - 64;
        const int sid = seg[n];
        const float ra = neighbours[n*(long)(T*2) + (T-1)*2 + 0] - agent_traj[(long)sid*(T*2) + (T-1)*2 + 0];
        const float rbv= neighbours[n*(long)(T*2) + (T-1)*2 + 1] - agent_traj[(long)sid*(T*2) + (T-1)*2 + 1];
        v = fmaf(rW[o*2+0], ra, fmaf(rW[o*2+1], rbv, rb[o]));
    }
    x0hi[n*128 + j] = f2bf(v);
    x0lo[n*128 + j] = f2bf(v - bf_hi(v));
}

// ---------------------------------------------------------------------------
// Weight prep: frag-order bf16 hi/lo split, optional per-K scale fold.
// ---------------------------------------------------------------------------
__global__ __launch_bounds__(64) void prep_wfrag(
    const float* __restrict__ W, const float* __restrict__ sc, int K,
    unsigned short* __restrict__ Whi, unsigned short* __restrict__ Wlo)
{
    const int nKc = K >> 5;
    const int blk = blockIdx.x;
    const int ti = blk / nKc, kc = blk - ti * nKc;
    const int l = threadIdx.x;
    const int n = ti * 16 + (l & 15);
    const int k0 = kc * 32 + (l >> 4) * 8;
    const long ob = ((long)blk * 64 + l) * 8;
#pragma unroll
    for (int j = 0; j < 8; ++j) {
        float v = W[(long)n * K + k0 + j];
        if (sc) v *= sc[k0 + j];
        Whi[ob + j] = f2bf(v);
        Wlo[ob + j] = f2bf(v - bf_hi(v));
    }
}

// bias fold: b'[n] = b[n] + sum_k sh[k]*W[n,k]  (sh may be null). grid=O, blk=64
__global__ __launch_bounds__(64) void prep_bias(
    const float* __restrict__ W, const float* __restrict__ sh,
    const float* __restrict__ b, int K, float* __restrict__ bout)
{
    const int n = blockIdx.x;
    const int l = threadIdx.x;
    float s = 0.f;
    if (sh)
        for (int k = l; k < K; k += 64) s += sh[k] * W[(long)n * K + k];
#pragma unroll
    for (int m = 32; m >= 1; m >>= 1) s += __shfl_xor(s, m, 64);
    if (l == 0) bout[n] = b[n] + s;
}

// ---------------------------------------------------------------------------
// Split-activation MFMA GEMM, BARRIER-FREE K-loop: A fragments are loaded
// straight from global (16B/lane, 64B row segments; panel is L2-resident via
// the XCD swizzle, R11-verified). No LDS staging -> no __syncthreads in the
// K-loop -> compiler pipelines loads vs MFMA with fine-grained vmcnt.
// launch_bounds (256,2): R10 measured (256,4) forces spill — do not raise.
// Requires gridDim.y % 8 == 0. Modes: Yf | Yhi/Ylo | segp+poolmax. Optional
// fused column stats into accum[2*O].
// ---------------------------------------------------------------------------
__global__ __launch_bounds__(256, 2) void gemm_split(
    const unsigned short* __restrict__ Ahi,
    const unsigned short* __restrict__ Alo,
    const unsigned short* __restrict__ Whi,
    const unsigned short* __restrict__ Wlo,
    const float* __restrict__ bias,
    float* __restrict__ Yf,
    unsigned short* __restrict__ Yhi,
    unsigned short* __restrict__ Ylo,
    float* __restrict__ accum,
    const int* __restrict__ segp,
    float* __restrict__ poolmax,
    int M, int K, int O)
{
    __shared__ int segl[128];
    const int t = threadIdx.x;
    const int lane = t & 63;
    const int w = t >> 6;
    const int wm = w & 1, wn = w >> 1;

    // XCD swizzle: flat -> (row panel, col panel)
    const int nx = gridDim.x;
    const int flat = blockIdx.y * nx + blockIdx.x;
    const int grp = flat / (8 * nx);
    const int loc = flat - grp * (8 * nx);
    const int m0 = (grp * 8 + (loc & 7)) * 128;
    const int n0 = (loc >> 3) * 128;
    const int nKc = K >> 5;

    f32x4 acc[4][4];
#pragma unroll
    for (int mt = 0; mt < 4; ++mt)
#pragma unroll
    for (int nt = 0; nt < 4; ++nt) acc[mt][nt] = (f32x4)0.f;

    const int arow = m0 + wm * 64 + (lane & 15);
    const int acol = (lane >> 4) * 8;
    const long bt0 = (long)((n0 >> 4) + wn * 4);

    for (int kc = 0; kc < nKc; ++kc) {
        BFrag afh[4], afl[4], bh[4], bl[4];
        const long kb = (long)kc * 32 + acol;
#pragma unroll
        for (int mt = 0; mt < 4; ++mt) {
            const long ao = (long)(arow + mt * 16) * K + kb;
            afh[mt].u = *(const uint4*)(Ahi + ao);
            afl[mt].u = *(const uint4*)(Alo + ao);
        }
#pragma unroll
        for (int nt = 0; nt < 4; ++nt) {
            const long fb = ((bt0 + nt) * nKc + kc) * 512 + lane * 8;
            bh[nt].u = *(const uint4*)(Whi + fb);
            bl[nt].u = *(const uint4*)(Wlo + fb);
        }
#pragma unroll
        for (int nt = 0; nt < 4; ++nt)
#pragma unroll
        for (int mt = 0; mt < 4; ++mt) {
            f32x4 a = acc[mt][nt];
            a = __builtin_amdgcn_mfma_f32_16x16x32_bf16(afh[mt].v, bh[nt].v, a, 0, 0, 0);
            a = __builtin_amdgcn_mfma_f32_16x16x32_bf16(afh[mt].v, bl[nt].v, a, 0, 0, 0);
            a = __builtin_amdgcn_mfma_f32_16x16x32_bf16(afl[mt].v, bh[nt].v, a, 0, 0, 0);
            acc[mt][nt] = a;
        }
    }

    if (segp) {
        if (t < 128) segl[t] = segp[m0 + t];
        __syncthreads();
    }

    const int cn = lane & 15, cq = lane >> 4;
#pragma unroll
    for (int nt = 0; nt < 4; ++nt) {
        const int n = n0 + wn * 64 + nt * 16 + cn;
        const float bs = bias[n];
        float s = 0.f, ssq = 0.f;
#pragma unroll
        for (int mt = 0; mt < 4; ++mt) {
            const int mb = wm * 64 + mt * 16 + cq * 4;
            float vmax = 0.f; int sid = -1;
#pragma unroll
            for (int r = 0; r < 4; ++r) {
                const float v = fmaxf(acc[mt][nt][r] + bs, 0.f);
                s += v; ssq += v * v;
                if (segp) {
                    const int sr = segl[mb + r];
                    if (r == 0) { vmax = v; sid = sr; }
                    else if (sr == sid) { vmax = fmaxf(vmax, v); }
                    else {
                        if (vmax > 0.f)
                            atomicMax((int*)&poolmax[(long)sid * O + n], __float_as_int(vmax));
                        sid = sr; vmax = v;
                    }
                } else if (Yf) {
                    Yf[(long)(m0 + mb + r) * O + n] = v;
                } else {
                    const long idx = (long)(m0 + mb + r) * O + n;
                    Yhi[idx] = f2bf(v);
                    Ylo[idx] = f2bf(v - bf_hi(v));
                }
            }
            if (segp && vmax > 0.f)
                atomicMax((int*)&poolmax[(long)sid * O + n], __float_as_int(vmax));
        }
        if (accum) {
            s   += __shfl_xor(s, 16, 64);   ssq += __shfl_xor(ssq, 16, 64);
            s   += __shfl_xor(s, 32, 64);   ssq += __shfl_xor(ssq, 32, 64);
            if (cq == 0) {
                atomicAdd(&accum[n], s);
                atomicAdd(&accum[O + n], ssq);
            }
        }
    }
}

// ---------------------------------------------------------------------------
// Column sums / sumsq (fp32). grid = (O/64, chunks). Used only for t2.
// ---------------------------------------------------------------------------
__global__ __launch_bounds__(256) void colstats(
    const float* __restrict__ Y, int M, int O, int chunkRows,
    float* __restrict__ accum)
{
    const int c = blockIdx.x * 64 + (threadIdx.x & 63);
    const int rgrp = threadIdx.x >> 6;
    const int r0 = blockIdx.y * chunkRows;
    int rend = r0 + chunkRows; if (rend > M) rend = M;
    float s = 0.f, ss = 0.f;
    for (int r = r0 + rgrp; r < rend; r += 4) {
        const float v = Y[(long)r*O + c];
        s += v; ss += v*v;
    }
    __shared__ float l1[256], l2[256];
    l1[threadIdx.x] = s; l2[threadIdx.x] = ss;
    __syncthreads();
    if (threadIdx.x < 64) {
        const int c2 = blockIdx.x * 64 + threadIdx.x;
        s  = l1[threadIdx.x] + l1[threadIdx.x+64] + l1[threadIdx.x+128] + l1[threadIdx.x+192];
        ss = l2[threadIdx.x] + l2[threadIdx.x+64] + l2[threadIdx.x+128] + l2[threadIdx.x+192];
        atomicAdd(&accum[c2], s);
        atomicAdd(&accum[O + c2], ss);
    }
}

__global__ __launch_bounds__(256) void bn_finalize(
    const float* __restrict__ accum, const float* __restrict__ g,
    const float* __restrict__ be, int O, float invM,
    float* __restrict__ scale, float* __restrict__ shift)
{
    const int o = blockIdx.x * 256 + threadIdx.x;
    if (o < O) {
        const float mean = accum[o] * invM;
        const float var  = accum[O + o] * invM - mean * mean;
        const float sc   = g[o] * rsqrtf(var + EPS_BN);
        scale[o] = sc;
        shift[o] = be[o] - mean * sc;
    }
}

// ---------------------------------------------------------------------------
// d0 = concat( BN2-affine(poolmax) or 0 (empty segment), agent_h ) -> hi/lo
// ---------------------------------------------------------------------------
__global__ __launch_bounds__(256) void build_d0(
    const float* __restrict__ poolraw, const float* __restrict__ agent_h,
    const int* __restrict__ seg, int N,
    const float* __restrict__ sc2, const float* __restrict__ sh2,
    unsigned short* __restrict__ d0hi, unsigned short* __restrict__ d0lo)
{
    const int b = blockIdx.x;
    int l = 0, h = N;
    while (l < h) { const int mid = (l + h) >> 1; if (seg[mid] < b) l = mid + 1; else h = mid; }
    const bool nonempty = (l < N) && (seg[l] == b);
    for (int c = threadIdx.x; c < 1088; c += 256) {
        float v;
        if (c < 1024) {
            v = nonempty ? fmaf(sc2[c], poolraw[(long)b*1024 + c], sh2[c]) : 0.f;
        } else {
            v = agent_h[(long)b*64 + (c - 1024)];
        }
        d0hi[(long)b*1088 + c] = f2bf(v);
        d0lo[(long)b*1088 + c] = f2bf(v - bf_hi(v));
    }
}

// ---------------------------------------------------------------------------
// i2 K-split partial GEMM (fp32, O=64): grid (M/128, KS).
// ---------------------------------------------------------------------------
__global__ __launch_bounds__(256) void gemm_i2_part(
    const float* __restrict__ A,   // [M, K] fp32
    const float* __restrict__ W,   // [64, K]
    const float* __restrict__ ascale, const float* __restrict__ ashift,
    float* __restrict__ part, int M, int K, int kchunk)
{
    __shared__ float As[16][132];
    __shared__ float Bs[16][68];
    const int t = threadIdx.x;
    const int m0 = blockIdx.x * 128;
    const int ks = blockIdx.y;
    const int kbeg = ks * kchunk;
    const int kend = kbeg + kchunk;
    const int tm = (t & 15) * 8;
    const int tn = (t >> 4) * 4;
    const int ar = t >> 1;          // 0..127
    const int ac = (t & 1) * 8;     // 0 or 8
    const int br = t >> 2;          // 0..63
    const int bc = (t & 3) * 4;     // 0,4,8,12

    float acc[8][4];
#pragma unroll
    for (int i = 0; i < 8; ++i)
#pragma unroll
    for (int j = 0; j < 4; ++j) acc[i][j] = 0.f;

    for (int k0 = kbeg; k0 < kend; k0 += 16) {
        float4 a0 = *(const float4*)&A[(long)(m0+ar)*K + k0 + ac];
        float4 a1 = *(const float4*)&A[(long)(m0+ar)*K + k0 + ac + 4];
        float4 s0 = *(const float4*)&ascale[k0 + ac];
        float4 s1 = *(const float4*)&ascale[k0 + ac + 4];
        float4 h0 = *(const float4*)&ashift[k0 + ac];
        float4 h1 = *(const float4*)&ashift[k0 + ac + 4];
        a0.x = fmaf(a0.x, s0.x, h0.x); a0.y = fmaf(a0.y, s0.y, h0.y);
        a0.z = fmaf(a0.z, s0.z, h0.z); a0.w = fmaf(a0.w, s0.w, h0.w);
        a1.x = fmaf(a1.x, s1.x, h1.x); a1.y = fmaf(a1.y, s1.y, h1.y);
        a1.z = fmaf(a1.z, s1.z, h1.z); a1.w = fmaf(a1.w, s1.w, h1.w);
        float4 b0 = *(const float4*)&W[(long)br*K + k0 + bc];
        __syncthreads();
        As[ac+0][ar] = a0.x; As[ac+1][ar] = a0.y; As[ac+2][ar] = a0.z; As[ac+3][ar] = a0.w;
        As[ac+4][ar] = a1.x; As[ac+5][ar] = a1.y; As[ac+6][ar] = a1.z; As[ac+7][ar] = a1.w;
        Bs[bc+0][br] = b0.x; Bs[bc+1][br] = b0.y; Bs[bc+2][br] = b0.z; Bs[bc+3][br] = b0.w;
        __syncthreads();
#pragma unroll
        for (int kk = 0; kk < 16; ++kk) {
            float av[8], bv[4];
            *(float4*)&av[0] = *(const float4*)&As[kk][tm];
            *(float4*)&av[4] = *(const float4*)&As[kk][tm + 4];
            *(float4*)&bv[0] = *(const float4*)&Bs[kk][tn];
#pragma unroll
            for (int i = 0; i < 8; ++i)
#pragma unroll
            for (int j = 0; j < 4; ++j)
                acc[i][j] = fmaf(av[i], bv[j], acc[i][j]);
        }
    }

    float* po = part + (long)ks * M * 64;
#pragma unroll
    for (int i = 0; i < 8; ++i)
        *(float4*)&po[(long)(m0 + tm + i) * 64 + tn] = *(float4*)&acc[i][0];
}

// t2 = relu(sum_ks part + bias). grid = M*64/256.
__global__ __launch_bounds__(256) void i2_finish(
    const float* __restrict__ part, const float* __restrict__ bias,
    int M, int KS, float* __restrict__ t2)
{
    const long idx = (long)blockIdx.x * 256 + threadIdx.x;
    if (idx < (long)M * 64) {
        float s = 0.f;
        for (int ks = 0; ks < KS; ++ks) s += part[(long)ks * M * 64 + idx];
        t2[idx] = fmaxf(s + bias[idx & 63], 0.f);
    }
}

// decoder weights: Wc = dW_ih + dW_hh, bc = db_ih + db_hh
__global__ __launch_bounds__(256) void prep_dec(
    const float* __restrict__ dW_ih, const float* __restrict__ dW_hh,
    const float* __restrict__ db_ih, const float* __restrict__ db_hh,
    float* __restrict__ Wc, float* __restrict__ bc)
{
    const int idx = blockIdx.x * 256 + threadIdx.x;
    if (idx < 256*64) Wc[idx] = dW_ih[idx] + dW_hh[idx];
    else if (idx < 256*64 + 256) bc[idx - 256*64] = db_ih[idx - 256*64] + db_hh[idx - 256*64];
}

// ---------------------------------------------------------------------------
// Autoregressive decoder: 30 LSTMCell steps (input == h), fused prediction.
// ---------------------------------------------------------------------------
__global__ __launch_bounds__(256) void decoder_kernel(
    const float* __restrict__ t2, const float* __restrict__ sc4,
    const float* __restrict__ sh4, const float* __restrict__ agent_c,
    const float* __restrict__ Wc, const float* __restrict__ bc,
    const float* __restrict__ pW, const float* __restrict__ pb,
    float* __restrict__ pred /*[B,30,2]*/)
{
    __shared__ float h_lds[2][64];
    __shared__ float zg_lds[2][64];
    __shared__ float zo_lds[2][64];
    const int t = threadIdx.x;
    const int lane = t & 63;
    const int wave = t >> 6;
    const int s = wave >> 1;
    const int role = wave & 1;
    const long seq = (long)blockIdx.x * 2 + s;

    const int r0 = role * 128 + lane;
    const int r1 = r0 + 64;
    float w0[64], w1[64];
#pragma unroll
    for (int k = 0; k < 64; k += 4) {
        float4 va = *(const float4*)&Wc[r0 * 64 + k];
        w0[k] = va.x; w0[k+1] = va.y; w0[k+2] = va.z; w0[k+3] = va.w;
        float4 vb = *(const float4*)&Wc[r1 * 64 + k];
        w1[k] = vb.x; w1[k+1] = vb.y; w1[k+2] = vb.z; w1[k+3] = vb.w;
    }
    const float bias0 = bc[r0];
    const float bias1 = bc[r1];
    const float pw0 = pW[lane], pw1 = pW[64 + lane];
    const float pb0 = pb[0], pb1 = pb[1];

    float c = agent_c[seq*64 + lane];
    if (role == 0)
        h_lds[s][lane] = fmaf(sc4[lane], t2[seq*64 + lane], sh4[lane]);
    __syncthreads();
    float hv = h_lds[s][lane];

    for (int step = 0; step < 30; ++step) {
        float z0 = bias0, z1 = bias1;
#pragma unroll
        for (int k = 0; k < 64; ++k) {
            float hk = __int_as_float(__builtin_amdgcn_readlane(__float_as_int(hv), k));
            z0 = fmaf(hk, w0[k], z0);
            z1 = fmaf(hk, w1[k], z1);
        }
        if (role == 1) { zg_lds[s][lane] = z0; zo_lds[s][lane] = z1; }
        __syncthreads();
        if (role == 0) {
            const float ig = sigmoid_f(z0);
            const float fg = sigmoid_f(z1);
            const float gg = tanh_f(zg_lds[s][lane]);
            const float og = sigmoid_f(zo_lds[s][lane]);
            c = fmaf(fg, c, ig * gg);
            h_lds[s][lane] = og * tanh_f(c);
        }
        __syncthreads();
        hv = h_lds[s][lane];
        if (role == 0) {
            float p0 = hv * pw0;
            float p1 = hv * pw1;
#pragma unroll
            for (int m = 32; m >= 1; m >>= 1) {
                p0 += __shfl_xor(p0, m, 64);
                p1 += __shfl_xor(p1, m, 64);
            }
            if (lane == 0) {
                pred[seq*60 + step*2 + 0] = p0 + pb0;
                pred[seq*60 + step*2 + 1] = p1 + pb1;
            }
        }
    }
}

// ---------------------------------------------------------------------------
extern "C" void kernel_launch(void* const* d_in, const int* in_sizes, int n_in,
                              void* d_out, int out_size, void* d_ws, size_t ws_size,
                              hipStream_t stream)
{
    const float* agent_traj = (const float*)d_in[0];
    const float* neighbours = (const float*)d_in[1];
    const float* aW_ih = (const float*)d_in[2];
    const float* aW_hh = (const float*)d_in[3];
    const float* ab_ih = (const float*)d_in[4];
    const float* ab_hh = (const float*)d_in[5];
    const float* nW_ih = (const float*)d_in[6];
    const float* nW_hh = (const float*)d_in[7];
    const float* nb_ih = (const float*)d_in[8];
    const float* nb_hh = (const float*)d_in[9];
    const float* dW_ih = (const float*)d_in[10];
    const float* dW_hh = (const float*)d_in[11];
    const float* db_ih = (const float*)d_in[12];
    const float* db_hh = (const float*)d_in[13];
    const float* pW = (const float*)d_in[14];
    const float* pb = (const float*)d_in[15];
    const float* rW = (const float*)d_in[16];
    const float* rb = (const float*)d_in[17];
    const float* m1W = (const float*)d_in[18];
    const float* m1b = (const float*)d_in[19];
    const float* g1  = (const float*)d_in[20];
    const float* be1 = (const float*)d_in[21];
    const float* m2W = (const float*)d_in[22];
    const float* m2b = (const float*)d_in[23];
    const float* g2  = (const float*)d_in[24];
    const float* be2 = (const float*)d_in[25];
    const float* i1W = (const float*)d_in[26];
    const float* i1b = (const float*)d_in[27];
    const float* ig1 = (const float*)d_in[28];
    const float* ib1 = (const float*)d_in[29];
    const float* i2W = (const float*)d_in[30];
    const float* i2b = (const float*)d_in[31];
    const float* ig2 = (const float*)d_in[32];
    const float* ib2 = (const float*)d_in[33];
    const int*   seg = (const int*)d_in[34];
    float* pred = (float*)d_out;

    const int B = 2048, T = 20, N = 32768;

    char* p = (char*)d_ws;
    auto alloc = [&](size_t bytes) -> char* {
        char* r = p; p += (bytes + 255) & ~(size_t)255; return r;
    };
    float* agent_h = (float*)alloc((size_t)B*64*4);
    float* agent_c = (float*)alloc((size_t)B*64*4);
    char* neigh_region = alloc((size_t)N*64*4);          // neigh_h, later t1 (fp32 B*1024)
    unsigned short* x0hi = (unsigned short*)alloc((size_t)N*128*2);
    unsigned short* x0lo = (unsigned short*)alloc((size_t)N*128*2);
    char* y1hi_region  = alloc((size_t)N*512*2);         // y1hi, later d0hi/d0lo/t2
    unsigned short* y1lo = (unsigned short*)alloc((size_t)N*512*2);
    float* poolraw = (float*)alloc((size_t)B*1024*4);    // 8 MB, zero-init
    float* accAll = (float*)alloc((size_t)(1024+2048+2048+128)*4);
    float* acc1 = accAll;            // 2*512
    float* acc2 = accAll + 1024;     // 2*1024
    float* acc3 = accAll + 3072;     // 2*1024
    float* acc4 = accAll + 5120;     // 2*64
    float* sc1 = (float*)alloc(512*4);  float* sh1 = (float*)alloc(512*4);
    float* sc2 = (float*)alloc(1024*4); float* sh2 = (float*)alloc(1024*4);
    float* sc3 = (float*)alloc(1024*4); float* sh3 = (float*)alloc(1024*4);
    float* sc4 = (float*)alloc(64*4);   float* sh4 = (float*)alloc(64*4);
    float* Wc = (float*)alloc(256*64*4);
    float* bc = (float*)alloc(256*4);
    unsigned short* W1hi = (unsigned short*)alloc((size_t)512*128*2);
    unsigned short* W1lo = (unsigned short*)alloc((size_t)512*128*2);
    unsigned short* W2hi = (unsigned short*)alloc((size_t)1024*512*2);
    unsigned short* W2lo = (unsigned short*)alloc((size_t)1024*512*2);
    unsigned short* Wi1hi = (unsigned short*)alloc((size_t)1024*1088*2);
    unsigned short* Wi1lo = (unsigned short*)alloc((size_t)1024*1088*2);
    float* b1f = (float*)alloc(512*4);
    float* b2f = (float*)alloc(1024*4);
    float* bi1f = (float*)alloc(1024*4);
    float* i2part = (float*)alloc((size_t)8*B*64*4);     // 4 MB partials

    // aliases (lifetimes disjoint, stream-ordered)
    float* neigh_h = (float*)neigh_region;
    float* t1      = (float*)neigh_region;       // after build_x0
    unsigned short* y1hi = (unsigned short*)y1hi_region;
    unsigned short* d0hi = (unsigned short*)y1hi_region;          // after MLP2
    unsigned short* d0lo = d0hi + (size_t)B*1088;
    float* t2 = (float*)(y1hi_region + (size_t)2*B*1088*2);

    hipMemsetAsync(accAll, 0, (1024+2048+2048+128)*sizeof(float), stream);
    hipMemsetAsync(poolraw, 0, (size_t)B*1024*4, stream);

    // weight preps that need no BN stats
    prep_wfrag<<<(512/16)*(128/32), 64, 0, stream>>>(m1W, nullptr, 128, W1hi, W1lo);
    prep_bias<<<512, 64, 0, stream>>>(m1W, nullptr, m1b, 128, b1f);
    prep_wfrag<<<(1024/16)*(1088/32), 64, 0, stream>>>(i1W, nullptr, 1088, Wi1hi, Wi1lo);
    prep_bias<<<1024, 64, 0, stream>>>(i1W, nullptr, i1b, 1088, bi1f);
    prep_dec<<<65, 256, 0, stream>>>(dW_ih, dW_hh, db_ih, db_hh, Wc, bc);

    lstm_mfma<<<B/16, 256, 0, stream>>>(agent_traj, aW_ih, aW_hh, ab_ih, ab_hh,
                                        agent_h, agent_c, T);
    lstm_mfma<<<N/16, 256, 0, stream>>>(neighbours, nW_ih, nW_hh, nb_ih, nb_hh,
                                        neigh_h, nullptr, T);
    build_x0<<<N/2, 256, 0, stream>>>(neigh_h, neighbours, agent_traj, seg, rW, rb,
                                      x0hi, x0lo, T);

    // MLP1 (fused colstats -> acc1)
    gemm_split<<<dim3(512/128, N/128), 256, 0, stream>>>(
        x0hi, x0lo, W1hi, W1lo, b1f, nullptr, y1hi, y1lo, acc1,
        nullptr, nullptr, N, 128, 512);
    bn_finalize<<<2, 256, 0, stream>>>(acc1, g1, be1, 512, 1.0f/N, sc1, sh1);

    // fold BN1 into W2
    prep_wfrag<<<(1024/16)*(512/32), 64, 0, stream>>>(m2W, sc1, 512, W2hi, W2lo);
    prep_bias<<<1024, 64, 0, stream>>>(m2W, sh1, m2b, 512, b2f);

    // MLP2 (fused colstats -> acc2, fused segment-max -> poolraw; y2 never hits HBM)
    gemm_split<<<dim3(1024/128, N/128), 256, 0, stream>>>(
        y1hi, y1lo, W2hi, W2lo, b2f, nullptr, nullptr, nullptr, acc2,
        seg, poolraw, N, 512, 1024);
    bn_finalize<<<4, 256, 0, stream>>>(acc2, g2, be2, 1024, 1.0f/N, sc2, sh2);

    build_d0<<<B, 256, 0, stream>>>(poolraw, agent_h, seg, N, sc2, sh2, d0hi, d0lo);

    // i1 (fused colstats -> acc3)
    gemm_split<<<dim3(1024/128, B/128), 256, 0, stream>>>(
        d0hi, d0lo, Wi1hi, Wi1lo, bi1f, t1, nullptr, nullptr, acc3,
        nullptr, nullptr, B, 1088, 1024);
    bn_finalize<<<4, 256, 0, stream>>>(acc3, ig1, ib1, 1024, 1.0f/B, sc3, sh3);

    // i2: K-split partials + finish
    gemm_i2_part<<<dim3(B/128, 8), 256, 0, stream>>>(t1, i2W, sc3, sh3, i2part,
                                                     B, 1024, 128);
    i2_finish<<<(B*64)/256, 256, 0, stream>>>(i2part, i2b, B, 8, t2);
    colstats<<<dim3(1, 8), 256, 0, stream>>>(t2, B, 64, 256, acc4);
    bn_finalize<<<1, 256, 0, stream>>>(acc4, ig2, ib2, 64, 1.0f/B, sc4, sh4);

    decoder_kernel<<<B/2, 256, 0, stream>>>(t2, sc4, sh4, agent_c, Wc, bc, pW, pb, pred);
}

// Round 15
// 642.754 us; speedup vs baseline: 1.1765x; 1.1765x over previous
//
#include <hip/hip_runtime.h>

#define EPS_BN 1e-5f

typedef __attribute__((ext_vector_type(8))) short short8;
typedef __attribute__((ext_vector_type(4))) float f32x4;

__device__ __forceinline__ float fast_rcp(float x) { return __builtin_amdgcn_rcpf(x); }
__device__ __forceinline__ float sigmoid_f(float x) { return fast_rcp(1.0f + __expf(-x)); }
// robust tanh: no inf/inf NaN at large |x|
__device__ __forceinline__ float tanh_f(float x) { return 1.0f - 2.0f * fast_rcp(__expf(2.0f * x) + 1.0f); }

// round-to-nearest-even fp32 -> bf16 bits
__device__ __forceinline__ unsigned short f2bf(float f) {
    unsigned u = __float_as_uint(f);
    u += 0x7FFFu + ((u >> 16) & 1u);
    return (unsigned short)(u >> 16);
}
__device__ __forceinline__ unsigned pk_bf(float a, float b) {
    return (unsigned)f2bf(a) | ((unsigned)f2bf(b) << 16);
}
// value of the bf16 rounding (hi part); residual = f - bf_hi(f)
__device__ __forceinline__ float bf_hi(float f) {
    return __uint_as_float((unsigned)f2bf(f) << 16);
}
__device__ __forceinline__ float bf2f(unsigned short u) {
    return __uint_as_float((unsigned)u << 16);
}

union AFrag { short e[8]; short8 v; };
union BFrag { uint4 u; short8 v; };

// ---------------------------------------------------------------------------
// Split-precision MFMA LSTM encoder v3 (verified R13): 4 waves/block, cell-
// group distribution, in-register combine, double-buffered h_ex, 1 barrier.
// ---------------------------------------------------------------------------
__global__ __launch_bounds__(256, 2) void lstm_mfma(
    const float* __restrict__ x,      // [S, T, 2]
    const float* __restrict__ W_ih,   // [256, 2]
    const float* __restrict__ W_hh,   // [256, 64]
    const float* __restrict__ b_ih,   // [256]
    const float* __restrict__ b_hh,   // [256]
    float* __restrict__ h_out,        // [S, 64]
    float* __restrict__ c_out,        // [S, 64] or null
    int T)
{
    __shared__ unsigned h_ex[2][2][16 * 52];   // [buf][hi/lo]

    const int tid  = threadIdx.x;
    const int w    = tid >> 6;        // cell-group == wave
    const int lane = tid & 63;
    const int s    = lane & 15;       // sequence within the 16
    const int q    = lane >> 4;       // quad

    short8 ahi[4][3], alo[4][3];
#pragma unroll
    for (int gt = 0; gt < 4; ++gt) {
        const int n = gt * 64 + w * 16 + s;
#pragma unroll
        for (int kc = 0; kc < 2; ++kc) {
            const float* src = &W_hh[n * 64 + kc * 32 + q * 8];
            float4 v0 = *(const float4*)src;
            float4 v1 = *(const float4*)(src + 4);
            float v[8] = {v0.x, v0.y, v0.z, v0.w, v1.x, v1.y, v1.z, v1.w};
            AFrag a, b;
#pragma unroll
            for (int j = 0; j < 8; ++j) {
                a.e[j] = (short)f2bf(v[j]);
                b.e[j] = (short)f2bf(v[j] - bf_hi(v[j]));
            }
            ahi[gt][kc] = a.v;
            alo[gt][kc] = b.v;
        }
        AFrag a2, b2;
#pragma unroll
        for (int j = 0; j < 8; ++j) { a2.e[j] = 0; b2.e[j] = 0; }
        if (q == 0) {   // K rows 64(wi0), 65(wi1), 66(bias)
            const float wi0 = W_ih[n * 2 + 0];
            const float wi1 = W_ih[n * 2 + 1];
            const float bs  = b_ih[n] + b_hh[n];
            a2.e[0] = (short)f2bf(wi0); b2.e[0] = (short)f2bf(wi0 - bf_hi(wi0));
            a2.e[1] = (short)f2bf(wi1); b2.e[1] = (short)f2bf(wi1 - bf_hi(wi1));
            a2.e[2] = (short)f2bf(bs);  b2.e[2] = (short)f2bf(bs  - bf_hi(bs));
        }
        ahi[gt][2] = a2.v;
        alo[gt][2] = b2.v;
    }

    for (int i = tid; i < 2 * 2 * 16 * 52; i += 256) (&h_ex[0][0][0])[i] = 0u;
    __syncthreads();
    if (tid < 16) {   // s = tid
        h_ex[0][0][tid * 52 + 33] = pk_bf(1.0f, 0.0f);
        h_ex[1][0][tid * 52 + 33] = pk_bf(1.0f, 0.0f);
        float2 xv = *(const float2*)&x[((long)blockIdx.x * 16 + tid) * (long)(T * 2)];
        h_ex[0][0][tid * 52 + 32] = pk_bf(xv.x, xv.y);
        h_ex[0][1][tid * 52 + 32] = pk_bf(xv.x - bf_hi(xv.x), xv.y - bf_hi(xv.y));
    }
    __syncthreads();

    float creg[4] = {0.f, 0.f, 0.f, 0.f};

    for (int t = 0; t < T; ++t) {
        const int rb = t & 1, wb = rb ^ 1;
        BFrag bhi[3], blo[3];
#pragma unroll
        for (int kc = 0; kc < 3; ++kc) {
            const int off = s * 52 + kc * 16 + (q >> 1) * 8 + (q & 1) * 4;
            bhi[kc].u = *(const uint4*)&h_ex[rb][0][off];
            blo[kc].u = *(const uint4*)&h_ex[rb][1][off];
        }

        f32x4 acc[4];
#pragma unroll
        for (int gt = 0; gt < 4; ++gt) acc[gt] = (f32x4)0.f;

#pragma unroll
        for (int kc = 0; kc < 3; ++kc) {
            const short8 bh = bhi[kc].v;
            const short8 bl = blo[kc].v;
#pragma unroll
            for (int gt = 0; gt < 4; ++gt) {
                f32x4 a = acc[gt];
                a = __builtin_amdgcn_mfma_f32_16x16x32_bf16(ahi[gt][kc], bh, a, 0, 0, 0);
                a = __builtin_amdgcn_mfma_f32_16x16x32_bf16(ahi[gt][kc], bl, a, 0, 0, 0);
                a = __builtin_amdgcn_mfma_f32_16x16x32_bf16(alo[gt][kc], bh, a, 0, 0, 0);
                acc[gt] = a;
            }
        }

        float hval[4];
#pragma unroll
        for (int r = 0; r < 4; ++r) {
            const float c = fmaf(sigmoid_f(acc[1][r]), creg[r],
                                 sigmoid_f(acc[0][r]) * tanh_f(acc[2][r]));
            creg[r] = c;
            hval[r] = sigmoid_f(acc[3][r]) * tanh_f(c);
        }
        {
            const int w0 = s * 52 + w * 8 + q * 2;
            h_ex[wb][0][w0]     = pk_bf(hval[0], hval[1]);
            h_ex[wb][0][w0 + 1] = pk_bf(hval[2], hval[3]);
            h_ex[wb][1][w0]     = pk_bf(hval[0] - bf_hi(hval[0]), hval[1] - bf_hi(hval[1]));
            h_ex[wb][1][w0 + 1] = pk_bf(hval[2] - bf_hi(hval[2]), hval[3] - bf_hi(hval[3]));
        }
        if (tid < 16 && t + 1 < T) {
            float2 xv = *(const float2*)&x[((long)blockIdx.x * 16 + tid) * (long)(T * 2) + (t + 1) * 2];
            h_ex[wb][0][tid * 52 + 32] = pk_bf(xv.x, xv.y);
            h_ex[wb][1][tid * 52 + 32] = pk_bf(xv.x - bf_hi(xv.x), xv.y - bf_hi(xv.y));
        }
        if (t == T - 1) {
            const long seq = (long)blockIdx.x * 16 + s;
            const int j0 = w * 16 + q * 4;
            *(float4*)&h_out[seq * 64 + j0] = make_float4(hval[0], hval[1], hval[2], hval[3]);
            if (c_out)
                *(float4*)&c_out[seq * 64 + j0] = make_float4(creg[0], creg[1], creg[2], creg[3]);
        }
        __syncthreads();
    }
}

// ---------------------------------------------------------------------------
// x0[n] = concat(neigh_h[n], rel @ rW.T + rb)  -> hi/lo bf16 planes [N,128]
// ---------------------------------------------------------------------------
__global__ __launch_bounds__(256) void build_x0(
    const float* __restrict__ neigh_h, const float* __restrict__ neighbours,
    const float* __restrict__ agent_traj, const int* __restrict__ seg,
    const float* __restrict__ rW, const float* __restrict__ rb,
    unsigned short* __restrict__ x0hi, unsigned short* __restrict__ x0lo, int T)
{
    const long n = (long)blockIdx.x * 2 + (threadIdx.x >> 7);
    const int j = threadIdx.x & 127;
    float v;
    if (j < 64) {
        v = neigh_h[n*64 + j];
    } else {
        const int o = j - 64;
        const int sid = seg[n];
        const float ra = neighbours[n*(long)(T*2) + (T-1)*2 + 0] - agent_traj[(long)sid*(T*2) + (T-1)*2 + 0];
        const float rbv= neighbours[n*(long)(T*2) + (T-1)*2 + 1] - agent_traj[(long)sid*(T*2) + (T-1)*2 + 1];
        v = fmaf(rW[o*2+0], ra, fmaf(rW[o*2+1], rbv, rb[o]));
    }
    x0hi[n*128 + j] = f2bf(v);
    x0lo[n*128 + j] = f2bf(v - bf_hi(v));
}

// ---------------------------------------------------------------------------
// Weight prep: frag-order bf16 hi/lo split, optional per-K scale fold.
// ---------------------------------------------------------------------------
__global__ __launch_bounds__(64) void prep_wfrag(
    const float* __restrict__ W, const float* __restrict__ sc, int K,
    unsigned short* __restrict__ Whi, unsigned short* __restrict__ Wlo)
{
    const int nKc = K >> 5;
    const int blk = blockIdx.x;
    const int ti = blk / nKc, kc = blk - ti * nKc;
    const int l = threadIdx.x;
    const int n = ti * 16 + (l & 15);
    const int k0 = kc * 32 + (l >> 4) * 8;
    const long ob = ((long)blk * 64 + l) * 8;
#pragma unroll
    for (int j = 0; j < 8; ++j) {
        float v = W[(long)n * K + k0 + j];
        if (sc) v *= sc[k0 + j];
        Whi[ob + j] = f2bf(v);
        Wlo[ob + j] = f2bf(v - bf_hi(v));
    }
}

// bias fold: b'[n] = b[n] + sum_k sh[k]*W[n,k]  (sh may be null). grid=O, blk=64
__global__ __launch_bounds__(64) void prep_bias(
    const float* __restrict__ W, const float* __restrict__ sh,
    const float* __restrict__ b, int K, float* __restrict__ bout)
{
    const int n = blockIdx.x;
    const int l = threadIdx.x;
    float s = 0.f;
    if (sh)
        for (int k = l; k < K; k += 64) s += sh[k] * W[(long)n * K + k];
#pragma unroll
    for (int m = 32; m >= 1; m >>= 1) s += __shfl_xor(s, m, 64);
    if (l == 0) bout[n] = b[n] + s;
}

// ---------------------------------------------------------------------------
// Split-activation MFMA GEMM (R13-verified plateau): XCD-aware block swizzle
// (FETCH 270->44 MB), LDS A-tile double-buffered, one __syncthreads per kc.
// launch_bounds (256,2): R10 measured (256,4) forces VGPR 104->64 + 1.8 GB
// spill; R14 measured that removing LDS staging entirely regresses (compiler
// won't pipeline naked global loads: VGPR 72, MfmaUtil 19%). Do not change.
// nKc must be EVEN. Requires gridDim.y % 8 == 0.
// Modes: Yf (fp32) | Yhi/Ylo (bf16 planes) | segp+poolmax (fused segment-max).
// Optional fused column stats into accum[2*O].
// ---------------------------------------------------------------------------
__global__ __launch_bounds__(256, 2) void gemm_split(
    const unsigned short* __restrict__ Ahi,
    const unsigned short* __restrict__ Alo,
    const unsigned short* __restrict__ Whi,
    const unsigned short* __restrict__ Wlo,
    const float* __restrict__ bias,
    float* __restrict__ Yf,
    unsigned short* __restrict__ Yhi,
    unsigned short* __restrict__ Ylo,
    float* __restrict__ accum,
    const int* __restrict__ segp,
    float* __restrict__ poolmax,
    int M, int K, int O)
{
    __shared__ unsigned short As[2][2][128 * 56];   // [buf][hi/lo]
    __shared__ int segl[128];
    const int t = threadIdx.x;
    const int lane = t & 63;
    const int w = t >> 6;
    const int wm = w & 1, wn = w >> 1;

    // XCD swizzle: flat -> (row panel, col panel)
    const int nx = gridDim.x;
    const int flat = blockIdx.y * nx + blockIdx.x;
    const int grp = flat / (8 * nx);
    const int loc = flat - grp * (8 * nx);
    const int m0 = (grp * 8 + (loc & 7)) * 128;
    const int n0 = (loc >> 3) * 128;
    const int nKc = K >> 5;   // even

    f32x4 acc[4][4];
#pragma unroll
    for (int mt = 0; mt < 4; ++mt)
#pragma unroll
    for (int nt = 0; nt < 4; ++nt) acc[mt][nt] = (f32x4)0.f;

    const long aoff = (long)(m0 + (t >> 1)) * K + (t & 1) * 16;
    const unsigned short* aph = Ahi + aoff;
    const unsigned short* apl = Alo + aoff;
    const int so = (t >> 1) * 56 + (t & 1) * 16;
    const int arow = wm * 64 + (lane & 15);
    const int acol = (lane >> 4) * 8;
    const long bt0 = (long)((n0 >> 4) + wn * 4);

    uint4 rah0, rah1, ral0, ral1;
    auto loadAreg = [&](int kc) {
        rah0 = *(const uint4*)(aph + kc * 32);
        rah1 = *(const uint4*)(aph + kc * 32 + 8);
        ral0 = *(const uint4*)(apl + kc * 32);
        ral1 = *(const uint4*)(apl + kc * 32 + 8);
    };
    auto storeAs = [&](int buf) {
        *(uint4*)&As[buf][0][so] = rah0; *(uint4*)&As[buf][0][so + 8] = rah1;
        *(uint4*)&As[buf][1][so] = ral0; *(uint4*)&As[buf][1][so + 8] = ral1;
    };
    auto loadB = [&](BFrag* bh, BFrag* bl, int kc) {
#pragma unroll
        for (int nt = 0; nt < 4; ++nt) {
            const long fb = ((bt0 + nt) * nKc + kc) * 512 + lane * 8;
            bh[nt].u = *(const uint4*)(Whi + fb);
            bl[nt].u = *(const uint4*)(Wlo + fb);
        }
    };
    auto compute = [&](int buf, BFrag* bh, BFrag* bl) {
        BFrag afh[4], afl[4];
#pragma unroll
        for (int mt = 0; mt < 4; ++mt) {
            afh[mt].u = *(const uint4*)&As[buf][0][(arow + mt * 16) * 56 + acol];
            afl[mt].u = *(const uint4*)&As[buf][1][(arow + mt * 16) * 56 + acol];
        }
#pragma unroll
        for (int nt = 0; nt < 4; ++nt)
#pragma unroll
        for (int mt = 0; mt < 4; ++mt) {
            f32x4 a = acc[mt][nt];
            a = __builtin_amdgcn_mfma_f32_16x16x32_bf16(afh[mt].v, bh[nt].v, a, 0, 0, 0);
            a = __builtin_amdgcn_mfma_f32_16x16x32_bf16(afh[mt].v, bl[nt].v, a, 0, 0, 0);
            a = __builtin_amdgcn_mfma_f32_16x16x32_bf16(afl[mt].v, bh[nt].v, a, 0, 0, 0);
            acc[mt][nt] = a;
        }
    };

    BFrag bh0[4], bl0[4], bh1[4], bl1[4];
    loadAreg(0);
    loadB(bh0, bl0, 0);
    storeAs(0);
    __syncthreads();
    for (int kc = 0; kc < nKc; kc += 2) {
        loadAreg(kc + 1);
        loadB(bh1, bl1, kc + 1);
        compute(0, bh0, bl0);
        storeAs(1);
        __syncthreads();
        if (kc + 2 < nKc) {
            loadAreg(kc + 2);
            loadB(bh0, bl0, kc + 2);
        }
        compute(1, bh1, bl1);
        if (kc + 2 < nKc) {
            storeAs(0);
            __syncthreads();
        }
    }

    if (segp) {
        __syncthreads();
        if (t < 128) segl[t] = segp[m0 + t];
        __syncthreads();
    }

    const int cn = lane & 15, cq = lane >> 4;
#pragma unroll
    for (int nt = 0; nt < 4; ++nt) {
        const int n = n0 + wn * 64 + nt * 16 + cn;
        const float bs = bias[n];
        float s = 0.f, ssq = 0.f;
#pragma unroll
        for (int mt = 0; mt < 4; ++mt) {
            const int mb = wm * 64 + mt * 16 + cq * 4;
            float vmax = 0.f; int sid = -1;
#pragma unroll
            for (int r = 0; r < 4; ++r) {
                const float v = fmaxf(acc[mt][nt][r] + bs, 0.f);
                s += v; ssq += v * v;
                if (segp) {
                    const int sr = segl[mb + r];
                    if (r == 0) { vmax = v; sid = sr; }
                    else if (sr == sid) { vmax = fmaxf(vmax, v); }
                    else {
                        if (vmax > 0.f)
                            atomicMax((int*)&poolmax[(long)sid * O + n], __float_as_int(vmax));
                        sid = sr; vmax = v;
                    }
                } else if (Yf) {
                    Yf[(long)(m0 + mb + r) * O + n] = v;
                } else {
                    const long idx = (long)(m0 + mb + r) * O + n;
                    Yhi[idx] = f2bf(v);
                    Ylo[idx] = f2bf(v - bf_hi(v));
                }
            }
            if (segp && vmax > 0.f)
                atomicMax((int*)&poolmax[(long)sid * O + n], __float_as_int(vmax));
        }
        if (accum) {
            s   += __shfl_xor(s, 16, 64);   ssq += __shfl_xor(ssq, 16, 64);
            s   += __shfl_xor(s, 32, 64);   ssq += __shfl_xor(ssq, 32, 64);
            if (cq == 0) {
                atomicAdd(&accum[n], s);
                atomicAdd(&accum[O + n], ssq);
            }
        }
    }
}

// ---------------------------------------------------------------------------
// Column sums / sumsq (fp32). grid = (O/64, chunks). Used only for t2.
// ---------------------------------------------------------------------------
__global__ __launch_bounds__(256) void colstats(
    const float* __restrict__ Y, int M, int O, int chunkRows,
    float* __restrict__ accum)
{
    const int c = blockIdx.x * 64 + (threadIdx.x & 63);
    const int rgrp = threadIdx.x >> 6;
    const int r0 = blockIdx.y * chunkRows;
    int rend = r0 + chunkRows; if (rend > M) rend = M;
    float s = 0.f, ss = 0.f;
    for (int r = r0 + rgrp; r < rend; r += 4) {
        const float v = Y[(long)r*O + c];
        s += v; ss += v*v;
    }
    __shared__ float l1[256], l2[256];
    l1[threadIdx.x] = s; l2[threadIdx.x] = ss;
    __syncthreads();
    if (threadIdx.x < 64) {
        const int c2 = blockIdx.x * 64 + threadIdx.x;
        s  = l1[threadIdx.x] + l1[threadIdx.x+64] + l1[threadIdx.x+128] + l1[threadIdx.x+192];
        ss = l2[threadIdx.x] + l2[threadIdx.x+64] + l2[threadIdx.x+128] + l2[threadIdx.x+192];
        atomicAdd(&accum[c2], s);
        atomicAdd(&accum[O + c2], ss);
    }
}

__global__ __launch_bounds__(256) void bn_finalize(
    const float* __restrict__ accum, const float* __restrict__ g,
    const float* __restrict__ be, int O, float invM,
    float* __restrict__ scale, float* __restrict__ shift)
{
    const int o = blockIdx.x * 256 + threadIdx.x;
    if (o < O) {
        const float mean = accum[o] * invM;
        const float var  = accum[O + o] * invM - mean * mean;
        const float sc   = g[o] * rsqrtf(var + EPS_BN);
        scale[o] = sc;
        shift[o] = be[o] - mean * sc;
    }
}

// ---------------------------------------------------------------------------
// d0 = concat( BN2-affine(poolmax) or 0 (empty segment), agent_h ) -> hi/lo
// ---------------------------------------------------------------------------
__global__ __launch_bounds__(256) void build_d0(
    const float* __restrict__ poolraw, const float* __restrict__ agent_h,
    const int* __restrict__ seg, int N,
    const float* __restrict__ sc2, const float* __restrict__ sh2,
    unsigned short* __restrict__ d0hi, unsigned short* __restrict__ d0lo)
{
    const int b = blockIdx.x;
    int l = 0, h = N;
    while (l < h) { const int mid = (l + h) >> 1; if (seg[mid] < b) l = mid + 1; else h = mid; }
    const bool nonempty = (l < N) && (seg[l] == b);
    for (int c = threadIdx.x; c < 1088; c += 256) {
        float v;
        if (c < 1024) {
            v = nonempty ? fmaf(sc2[c], poolraw[(long)b*1024 + c], sh2[c]) : 0.f;
        } else {
            v = agent_h[(long)b*64 + (c - 1024)];
        }
        d0hi[(long)b*1088 + c] = f2bf(v);
        d0lo[(long)b*1088 + c] = f2bf(v - bf_hi(v));
    }
}

// ---------------------------------------------------------------------------
// i2 K-split partial GEMM (fp32, O=64): grid (M/128, KS).
// ---------------------------------------------------------------------------
__global__ __launch_bounds__(256) void gemm_i2_part(
    const float* __restrict__ A,   // [M, K] fp32
    const float* __restrict__ W,   // [64, K]
    const float* __restrict__ ascale, const float* __restrict__ ashift,
    float* __restrict__ part, int M, int K, int kchunk)
{
    __shared__ float As[16][132];
    __shared__ float Bs[16][68];
    const int t = threadIdx.x;
    const int m0 = blockIdx.x * 128;
    const int ks = blockIdx.y;
    const int kbeg = ks * kchunk;
    const int kend = kbeg + kchunk;
    const int tm = (t & 15) * 8;
    const int tn = (t >> 4) * 4;
    const int ar = t >> 1;          // 0..127
    const int ac = (t & 1) * 8;     // 0 or 8
    const int br = t >> 2;          // 0..63
    const int bc = (t & 3) * 4;     // 0,4,8,12

    float acc[8][4];
#pragma unroll
    for (int i = 0; i < 8; ++i)
#pragma unroll
    for (int j = 0; j < 4; ++j) acc[i][j] = 0.f;

    for (int k0 = kbeg; k0 < kend; k0 += 16) {
        float4 a0 = *(const float4*)&A[(long)(m0+ar)*K + k0 + ac];
        float4 a1 = *(const float4*)&A[(long)(m0+ar)*K + k0 + ac + 4];
        float4 s0 = *(const float4*)&ascale[k0 + ac];
        float4 s1 = *(const float4*)&ascale[k0 + ac + 4];
        float4 h0 = *(const float4*)&ashift[k0 + ac];
        float4 h1 = *(const float4*)&ashift[k0 + ac + 4];
        a0.x = fmaf(a0.x, s0.x, h0.x); a0.y = fmaf(a0.y, s0.y, h0.y);
        a0.z = fmaf(a0.z, s0.z, h0.z); a0.w = fmaf(a0.w, s0.w, h0.w);
        a1.x = fmaf(a1.x, s1.x, h1.x); a1.y = fmaf(a1.y, s1.y, h1.y);
        a1.z = fmaf(a1.z, s1.z, h1.z); a1.w = fmaf(a1.w, s1.w, h1.w);
        float4 b0 = *(const float4*)&W[(long)br*K + k0 + bc];
        __syncthreads();
        As[ac+0][ar] = a0.x; As[ac+1][ar] = a0.y; As[ac+2][ar] = a0.z; As[ac+3][ar] = a0.w;
        As[ac+4][ar] = a1.x; As[ac+5][ar] = a1.y; As[ac+6][ar] = a1.z; As[ac+7][ar] = a1.w;
        Bs[bc+0][br] = b0.x; Bs[bc+1][br] = b0.y; Bs[bc+2][br] = b0.z; Bs[bc+3][br] = b0.w;
        __syncthreads();
#pragma unroll
        for (int kk = 0; kk < 16; ++kk) {
            float av[8], bv[4];
            *(float4*)&av[0] = *(const float4*)&As[kk][tm];
            *(float4*)&av[4] = *(const float4*)&As[kk][tm + 4];
            *(float4*)&bv[0] = *(const float4*)&Bs[kk][tn];
#pragma unroll
            for (int i = 0; i < 8; ++i)
#pragma unroll
            for (int j = 0; j < 4; ++j)
                acc[i][j] = fmaf(av[i], bv[j], acc[i][j]);
        }
    }

    float* po = part + (long)ks * M * 64;
#pragma unroll
    for (int i = 0; i < 8; ++i)
        *(float4*)&po[(long)(m0 + tm + i) * 64 + tn] = *(float4*)&acc[i][0];
}

// t2 = relu(sum_ks part + bias). grid = M*64/256.
__global__ __launch_bounds__(256) void i2_finish(
    const float* __restrict__ part, const float* __restrict__ bias,
    int M, int KS, float* __restrict__ t2)
{
    const long idx = (long)blockIdx.x * 256 + threadIdx.x;
    if (idx < (long)M * 64) {
        float s = 0.f;
        for (int ks = 0; ks < KS; ++ks) s += part[(long)ks * M * 64 + idx];
        t2[idx] = fmaxf(s + bias[idx & 63], 0.f);
    }
}

// decoder weights: Wc = dW_ih + dW_hh, bc = db_ih + db_hh
__global__ __launch_bounds__(256) void prep_dec(
    const float* __restrict__ dW_ih, const float* __restrict__ dW_hh,
    const float* __restrict__ db_ih, const float* __restrict__ db_hh,
    float* __restrict__ Wc, float* __restrict__ bc)
{
    const int idx = blockIdx.x * 256 + threadIdx.x;
    if (idx < 256*64) Wc[idx] = dW_ih[idx] + dW_hh[idx];
    else if (idx < 256*64 + 256) bc[idx - 256*64] = db_ih[idx - 256*64] + db_hh[idx - 256*64];
}

// ---------------------------------------------------------------------------
// Autoregressive decoder: 30 LSTMCell steps (input == h), fused prediction.
// ---------------------------------------------------------------------------
__global__ __launch_bounds__(256) void decoder_kernel(
    const float* __restrict__ t2, const float* __restrict__ sc4,
    const float* __restrict__ sh4, const float* __restrict__ agent_c,
    const float* __restrict__ Wc, const float* __restrict__ bc,
    const float* __restrict__ pW, const float* __restrict__ pb,
    float* __restrict__ pred /*[B,30,2]*/)
{
    __shared__ float h_lds[2][64];
    __shared__ float zg_lds[2][64];
    __shared__ float zo_lds[2][64];
    const int t = threadIdx.x;
    const int lane = t & 63;
    const int wave = t >> 6;
    const int s = wave >> 1;
    const int role = wave & 1;
    const long seq = (long)blockIdx.x * 2 + s;

    const int r0 = role * 128 + lane;
    const int r1 = r0 + 64;
    float w0[64], w1[64];
#pragma unroll
    for (int k = 0; k < 64; k += 4) {
        float4 va = *(const float4*)&Wc[r0 * 64 + k];
        w0[k] = va.x; w0[k+1] = va.y; w0[k+2] = va.z; w0[k+3] = va.w;
        float4 vb = *(const float4*)&Wc[r1 * 64 + k];
        w1[k] = vb.x; w1[k+1] = vb.y; w1[k+2] = vb.z; w1[k+3] = vb.w;
    }
    const float bias0 = bc[r0];
    const float bias1 = bc[r1];
    const float pw0 = pW[lane], pw1 = pW[64 + lane];
    const float pb0 = pb[0], pb1 = pb[1];

    float c = agent_c[seq*64 + lane];
    if (role == 0)
        h_lds[s][lane] = fmaf(sc4[lane], t2[seq*64 + lane], sh4[lane]);
    __syncthreads();
    float hv = h_lds[s][lane];

    for (int step = 0; step < 30; ++step) {
        float z0 = bias0, z1 = bias1;
#pragma unroll
        for (int k = 0; k < 64; ++k) {
            float hk = __int_as_float(__builtin_amdgcn_readlane(__float_as_int(hv), k));
            z0 = fmaf(hk, w0[k], z0);
            z1 = fmaf(hk, w1[k], z1);
        }
        if (role == 1) { zg_lds[s][lane] = z0; zo_lds[s][lane] = z1; }
        __syncthreads();
        if (role == 0) {
            const float ig = sigmoid_f(z0);
            const float fg = sigmoid_f(z1);
            const float gg = tanh_f(zg_lds[s][lane]);
            const float og = sigmoid_f(zo_lds[s][lane]);
            c = fmaf(fg, c, ig * gg);
            h_lds[s][lane] = og * tanh_f(c);
        }
        __syncthreads();
        hv = h_lds[s][lane];
        if (role == 0) {
            float p0 = hv * pw0;
            float p1 = hv * pw1;
#pragma unroll
            for (int m = 32; m >= 1; m >>= 1) {
                p0 += __shfl_xor(p0, m, 64);
                p1 += __shfl_xor(p1, m, 64);
            }
            if (lane == 0) {
                pred[seq*60 + step*2 + 0] = p0 + pb0;
                pred[seq*60 + step*2 + 1] = p1 + pb1;
            }
        }
    }
}

// ---------------------------------------------------------------------------
extern "C" void kernel_launch(void* const* d_in, const int* in_sizes, int n_in,
                              void* d_out, int out_size, void* d_ws, size_t ws_size,
                              hipStream_t stream)
{
    const float* agent_traj = (const float*)d_in[0];
    const float* neighbours = (const float*)d_in[1];
    const float* aW_ih = (const float*)d_in[2];
    const float* aW_hh = (const float*)d_in[3];
    const float* ab_ih = (const float*)d_in[4];
    const float* ab_hh = (const float*)d_in[5];
    const float* nW_ih = (const float*)d_in[6];
    const float* nW_hh = (const float*)d_in[7];
    const float* nb_ih = (const float*)d_in[8];
    const float* nb_hh = (const float*)d_in[9];
    const float* dW_ih = (const float*)d_in[10];
    const float* dW_hh = (const float*)d_in[11];
    const float* db_ih = (const float*)d_in[12];
    const float* db_hh = (const float*)d_in[13];
    const float* pW = (const float*)d_in[14];
    const float* pb = (const float*)d_in[15];
    const float* rW = (const float*)d_in[16];
    const float* rb = (const float*)d_in[17];
    const float* m1W = (const float*)d_in[18];
    const float* m1b = (const float*)d_in[19];
    const float* g1  = (const float*)d_in[20];
    const float* be1 = (const float*)d_in[21];
    const float* m2W = (const float*)d_in[22];
    const float* m2b = (const float*)d_in[23];
    const float* g2  = (const float*)d_in[24];
    const float* be2 = (const float*)d_in[25];
    const float* i1W = (const float*)d_in[26];
    const float* i1b = (const float*)d_in[27];
    const float* ig1 = (const float*)d_in[28];
    const float* ib1 = (const float*)d_in[29];
    const float* i2W = (const float*)d_in[30];
    const float* i2b = (const float*)d_in[31];
    const float* ig2 = (const float*)d_in[32];
    const float* ib2 = (const float*)d_in[33];
    const int*   seg = (const int*)d_in[34];
    float* pred = (float*)d_out;

    const int B = 2048, T = 20, N = 32768;

    char* p = (char*)d_ws;
    auto alloc = [&](size_t bytes) -> char* {
        char* r = p; p += (bytes + 255) & ~(size_t)255; return r;
    };
    float* agent_h = (float*)alloc((size_t)B*64*4);
    float* agent_c = (float*)alloc((size_t)B*64*4);
    char* neigh_region = alloc((size_t)N*64*4);          // neigh_h, later t1 (fp32 B*1024)
    unsigned short* x0hi = (unsigned short*)alloc((size_t)N*128*2);
    unsigned short* x0lo = (unsigned short*)alloc((size_t)N*128*2);
    char* y1hi_region  = alloc((size_t)N*512*2);         // y1hi, later d0hi/d0lo/t2
    unsigned short* y1lo = (unsigned short*)alloc((size_t)N*512*2);
    float* poolraw = (float*)alloc((size_t)B*1024*4);    // 8 MB, zero-init
    float* accAll = (float*)alloc((size_t)(1024+2048+2048+128)*4);
    float* acc1 = accAll;            // 2*512
    float* acc2 = accAll + 1024;     // 2*1024
    float* acc3 = accAll + 3072;     // 2*1024
    float* acc4 = accAll + 5120;     // 2*64
    float* sc1 = (float*)alloc(512*4);  float* sh1 = (float*)alloc(512*4);
    float* sc2 = (float*)alloc(1024*4); float* sh2 = (float*)alloc(1024*4);
    float* sc3 = (float*)alloc(1024*4); float* sh3 = (float*)alloc(1024*4);
    float* sc4 = (float*)alloc(64*4);   float* sh4 = (float*)alloc(64*4);
    float* Wc = (float*)alloc(256*64*4);
    float* bc = (float*)alloc(256*4);
    unsigned short* W1hi = (unsigned short*)alloc((size_t)512*128*2);
    unsigned short* W1lo = (unsigned short*)alloc((size_t)512*128*2);
    unsigned short* W2hi = (unsigned short*)alloc((size_t)1024*512*2);
    unsigned short* W2lo = (unsigned short*)alloc((size_t)1024*512*2);
    unsigned short* Wi1hi = (unsigned short*)alloc((size_t)1024*1088*2);
    unsigned short* Wi1lo = (unsigned short*)alloc((size_t)1024*1088*2);
    float* b1f = (float*)alloc(512*4);
    float* b2f = (float*)alloc(1024*4);
    float* bi1f = (float*)alloc(1024*4);
    float* i2part = (float*)alloc((size_t)8*B*64*4);     // 4 MB partials

    // aliases (lifetimes disjoint, stream-ordered)
    float* neigh_h = (float*)neigh_region;
    float* t1      = (float*)neigh_region;       // after build_x0
    unsigned short* y1hi = (unsigned short*)y1hi_region;
    unsigned short* d0hi = (unsigned short*)y1hi_region;          // after MLP2
    unsigned short* d0lo = d0hi + (size_t)B*1088;
    float* t2 = (float*)(y1hi_region + (size_t)2*B*1088*2);

    hipMemsetAsync(accAll, 0, (1024+2048+2048+128)*sizeof(float), stream);
    hipMemsetAsync(poolraw, 0, (size_t)B*1024*4, stream);

    // weight preps that need no BN stats
    prep_wfrag<<<(512/16)*(128/32), 64, 0, stream>>>(m1W, nullptr, 128, W1hi, W1lo);
    prep_bias<<<512, 64, 0, stream>>>(m1W, nullptr, m1b, 128, b1f);
    prep_wfrag<<<(1024/16)*(1088/32), 64, 0, stream>>>(i1W, nullptr, 1088, Wi1hi, Wi1lo);
    prep_bias<<<1024, 64, 0, stream>>>(i1W, nullptr, i1b, 1088, bi1f);
    prep_dec<<<65, 256, 0, stream>>>(dW_ih, dW_hh, db_ih, db_hh, Wc, bc);

    lstm_mfma<<<B/16, 256, 0, stream>>>(agent_traj, aW_ih, aW_hh, ab_ih, ab_hh,
                                        agent_h, agent_c, T);
    lstm_mfma<<<N/16, 256, 0, stream>>>(neighbours, nW_ih, nW_hh, nb_ih, nb_hh,
                                        neigh_h, nullptr, T);
    build_x0<<<N/2, 256, 0, stream>>>(neigh_h, neighbours, agent_traj, seg, rW, rb,
                                      x0hi, x0lo, T);

    // MLP1 (fused colstats -> acc1)
    gemm_split<<<dim3(512/128, N/128), 256, 0, stream>>>(
        x0hi, x0lo, W1hi, W1lo, b1f, nullptr, y1hi, y1lo, acc1,
        nullptr, nullptr, N, 128, 512);
    bn_finalize<<<2, 256, 0, stream>>>(acc1, g1, be1, 512, 1.0f/N, sc1, sh1);

    // fold BN1 into W2
    prep_wfrag<<<(1024/16)*(512/32), 64, 0, stream>>>(m2W, sc1, 512, W2hi, W2lo);
    prep_bias<<<1024, 64, 0, stream>>>(m2W, sh1, m2b, 512, b2f);

    // MLP2 (fused colstats -> acc2, fused segment-max -> poolraw; y2 never hits HBM)
    gemm_split<<<dim3(1024/128, N/128), 256, 0, stream>>>(
        y1hi, y1lo, W2hi, W2lo, b2f, nullptr, nullptr, nullptr, acc2,
        seg, poolraw, N, 512, 1024);
    bn_finalize<<<4, 256, 0, stream>>>(acc2, g2, be2, 1024, 1.0f/N, sc2, sh2);

    build_d0<<<B, 256, 0, stream>>>(poolraw, agent_h, seg, N, sc2, sh2, d0hi, d0lo);

    // i1 (fused colstats -> acc3)
    gemm_split<<<dim3(1024/128, B/128), 256, 0, stream>>>(
        d0hi, d0lo, Wi1hi, Wi1lo, bi1f, t1, nullptr, nullptr, acc3,
        nullptr, nullptr, B, 1088, 1024);
    bn_finalize<<<4, 256, 0, stream>>>(acc3, ig1, ib1, 1024, 1.0f/B, sc3, sh3);

    // i2: K-split partials + finish
    gemm_i2_part<<<dim3(B/128, 8), 256, 0, stream>>>(t1, i2W, sc3, sh3, i2part,
                                                     B, 1024, 128);
    i2_finish<<<(B*64)/256, 256, 0, stream>>>(i2part, i2b, B, 8, t2);
    colstats<<<dim3(1, 8), 256, 0, stream>>>(t2, B, 64, 256, acc4);
    bn_finalize<<<1, 256, 0, stream>>>(acc4, ig2, ib2, 64, 1.0f/B, sc4, sh4);

    decoder_kernel<<<B/2, 256, 0, stream>>>(t2, sc4, sh4, agent_c, Wc, bc, pW, pb, pred);
}

// Round 16
// 631.639 us; speedup vs baseline: 1.1972x; 1.0176x over previous
//
#include <hip/hip_runtime.h>

#define EPS_BN 1e-5f

typedef __attribute__((ext_vector_type(8))) short short8;
typedef __attribute__((ext_vector_type(4))) float f32x4;

__device__ __forceinline__ float fast_rcp(float x) { return __builtin_amdgcn_rcpf(x); }
__device__ __forceinline__ float sigmoid_f(float x) { return fast_rcp(1.0f + __expf(-x)); }
// robust tanh: no inf/inf NaN at large |x|
__device__ __forceinline__ float tanh_f(float x) { return 1.0f - 2.0f * fast_rcp(__expf(2.0f * x) + 1.0f); }

// round-to-nearest-even fp32 -> bf16 bits
__device__ __forceinline__ unsigned short f2bf(float f) {
    unsigned u = __float_as_uint(f);
    u += 0x7FFFu + ((u >> 16) & 1u);
    return (unsigned short)(u >> 16);
}
__device__ __forceinline__ unsigned pk_bf(float a, float b) {
    return (unsigned)f2bf(a) | ((unsigned)f2bf(b) << 16);
}
// value of the bf16 rounding (hi part); residual = f - bf_hi(f)
__device__ __forceinline__ float bf_hi(float f) {
    return __uint_as_float((unsigned)f2bf(f) << 16);
}
__device__ __forceinline__ float bf2f(unsigned short u) {
    return __uint_as_float((unsigned)u << 16);
}

union AFrag { short e[8]; short8 v; };
union BFrag { uint4 u; short8 v; };

// ---------------------------------------------------------------------------
// Split-precision MFMA LSTM encoder v3 (verified R13) — MERGED dispatch:
// blocks [0, nAgent) run the agent sequences (with c_out), blocks
// [nAgent, nAgent+nNeigh) run the neighbour sequences. Role selection is
// wave-uniform (branch on blockIdx only); code path identical otherwise.
// 4 waves/block, cell-group distribution, in-register combine,
// double-buffered h_ex, exactly one __syncthreads per step.
// ---------------------------------------------------------------------------
__global__ __launch_bounds__(256, 2) void lstm_mfma(
    const float* __restrict__ xA,      // [SA, T, 2]
    const float* __restrict__ aW_ih, const float* __restrict__ aW_hh,
    const float* __restrict__ ab_ih, const float* __restrict__ ab_hh,
    float* __restrict__ agent_h, float* __restrict__ agent_c,
    const float* __restrict__ xN,      // [SN, T, 2]
    const float* __restrict__ nW_ih, const float* __restrict__ nW_hh,
    const float* __restrict__ nb_ih, const float* __restrict__ nb_hh,
    float* __restrict__ neigh_h,
    int nAgent, int T)
{
    __shared__ unsigned h_ex[2][2][16 * 52];   // [buf][hi/lo]

    const bool isA = (blockIdx.x < (unsigned)nAgent);
    const long blk = isA ? blockIdx.x : blockIdx.x - nAgent;
    const float* __restrict__ x     = isA ? xA   : xN;
    const float* __restrict__ W_ih  = isA ? aW_ih : nW_ih;
    const float* __restrict__ W_hh  = isA ? aW_hh : nW_hh;
    const float* __restrict__ b_ih  = isA ? ab_ih : nb_ih;
    const float* __restrict__ b_hh  = isA ? ab_hh : nb_hh;
    float* __restrict__ h_out = isA ? agent_h : neigh_h;
    float* __restrict__ c_out = isA ? agent_c : nullptr;

    const int tid  = threadIdx.x;
    const int w    = tid >> 6;        // cell-group == wave
    const int lane = tid & 63;
    const int s    = lane & 15;       // sequence within the 16
    const int q    = lane >> 4;       // quad

    short8 ahi[4][3], alo[4][3];
#pragma unroll
    for (int gt = 0; gt < 4; ++gt) {
        const int n = gt * 64 + w * 16 + s;
#pragma unroll
        for (int kc = 0; kc < 2; ++kc) {
            const float* src = &W_hh[n * 64 + kc * 32 + q * 8];
            float4 v0 = *(const float4*)src;
            float4 v1 = *(const float4*)(src + 4);
            float v[8] = {v0.x, v0.y, v0.z, v0.w, v1.x, v1.y, v1.z, v1.w};
            AFrag a, b;
#pragma unroll
            for (int j = 0; j < 8; ++j) {
                a.e[j] = (short)f2bf(v[j]);
                b.e[j] = (short)f2bf(v[j] - bf_hi(v[j]));
            }
            ahi[gt][kc] = a.v;
            alo[gt][kc] = b.v;
        }
        AFrag a2, b2;
#pragma unroll
        for (int j = 0; j < 8; ++j) { a2.e[j] = 0; b2.e[j] = 0; }
        if (q == 0) {   // K rows 64(wi0), 65(wi1), 66(bias)
            const float wi0 = W_ih[n * 2 + 0];
            const float wi1 = W_ih[n * 2 + 1];
            const float bs  = b_ih[n] + b_hh[n];
            a2.e[0] = (short)f2bf(wi0); b2.e[0] = (short)f2bf(wi0 - bf_hi(wi0));
            a2.e[1] = (short)f2bf(wi1); b2.e[1] = (short)f2bf(wi1 - bf_hi(wi1));
            a2.e[2] = (short)f2bf(bs);  b2.e[2] = (short)f2bf(bs  - bf_hi(bs));
        }
        ahi[gt][2] = a2.v;
        alo[gt][2] = b2.v;
    }

    for (int i = tid; i < 2 * 2 * 16 * 52; i += 256) (&h_ex[0][0][0])[i] = 0u;
    __syncthreads();
    if (tid < 16) {   // s = tid
        h_ex[0][0][tid * 52 + 33] = pk_bf(1.0f, 0.0f);
        h_ex[1][0][tid * 52 + 33] = pk_bf(1.0f, 0.0f);
        float2 xv = *(const float2*)&x[(blk * 16 + tid) * (long)(T * 2)];
        h_ex[0][0][tid * 52 + 32] = pk_bf(xv.x, xv.y);
        h_ex[0][1][tid * 52 + 32] = pk_bf(xv.x - bf_hi(xv.x), xv.y - bf_hi(xv.y));
    }
    __syncthreads();

    float creg[4] = {0.f, 0.f, 0.f, 0.f};

    for (int t = 0; t < T; ++t) {
        const int rb = t & 1, wb = rb ^ 1;
        BFrag bhi[3], blo[3];
#pragma unroll
        for (int kc = 0; kc < 3; ++kc) {
            const int off = s * 52 + kc * 16 + (q >> 1) * 8 + (q & 1) * 4;
            bhi[kc].u = *(const uint4*)&h_ex[rb][0][off];
            blo[kc].u = *(const uint4*)&h_ex[rb][1][off];
        }

        f32x4 acc[4];
#pragma unroll
        for (int gt = 0; gt < 4; ++gt) acc[gt] = (f32x4)0.f;

#pragma unroll
        for (int kc = 0; kc < 3; ++kc) {
            const short8 bh = bhi[kc].v;
            const short8 bl = blo[kc].v;
#pragma unroll
            for (int gt = 0; gt < 4; ++gt) {
                f32x4 a = acc[gt];
                a = __builtin_amdgcn_mfma_f32_16x16x32_bf16(ahi[gt][kc], bh, a, 0, 0, 0);
                a = __builtin_amdgcn_mfma_f32_16x16x32_bf16(ahi[gt][kc], bl, a, 0, 0, 0);
                a = __builtin_amdgcn_mfma_f32_16x16x32_bf16(alo[gt][kc], bh, a, 0, 0, 0);
                acc[gt] = a;
            }
        }

        float hval[4];
#pragma unroll
        for (int r = 0; r < 4; ++r) {
            const float c = fmaf(sigmoid_f(acc[1][r]), creg[r],
                                 sigmoid_f(acc[0][r]) * tanh_f(acc[2][r]));
            creg[r] = c;
            hval[r] = sigmoid_f(acc[3][r]) * tanh_f(c);
        }
        {
            const int w0 = s * 52 + w * 8 + q * 2;
            h_ex[wb][0][w0]     = pk_bf(hval[0], hval[1]);
            h_ex[wb][0][w0 + 1] = pk_bf(hval[2], hval[3]);
            h_ex[wb][1][w0]     = pk_bf(hval[0] - bf_hi(hval[0]), hval[1] - bf_hi(hval[1]));
            h_ex[wb][1][w0 + 1] = pk_bf(hval[2] - bf_hi(hval[2]), hval[3] - bf_hi(hval[3]));
        }
        if (tid < 16 && t + 1 < T) {
            float2 xv = *(const float2*)&x[(blk * 16 + tid) * (long)(T * 2) + (t + 1) * 2];
            h_ex[wb][0][tid * 52 + 32] = pk_bf(xv.x, xv.y);
            h_ex[wb][1][tid * 52 + 32] = pk_bf(xv.x - bf_hi(xv.x), xv.y - bf_hi(xv.y));
        }
        if (t == T - 1) {
            const long seq = blk * 16 + s;
            const int j0 = w * 16 + q * 4;
            *(float4*)&h_out[seq * 64 + j0] = make_float4(hval[0], hval[1], hval[2], hval[3]);
            if (c_out)
                *(float4*)&c_out[seq * 64 + j0] = make_float4(creg[0], creg[1], creg[2], creg[3]);
        }
        __syncthreads();
    }
}

// ---------------------------------------------------------------------------
// x0[n] = concat(neigh_h[n], rel @ rW.T + rb)  -> hi/lo bf16 planes [N,128]
// ---------------------------------------------------------------------------
__global__ __launch_bounds__(256) void build_x0(
    const float* __restrict__ neigh_h, const float* __restrict__ neighbours,
    const float* __restrict__ agent_traj, const int* __restrict__ seg,
    const float* __restrict__ rW, const float* __restrict__ rb,
    unsigned short* __restrict__ x0hi, unsigned short* __restrict__ x0lo, int T)
{
    const long n = (long)blockIdx.x * 2 + (threadIdx.x >> 7);
    const int j = threadIdx.x & 127;
    float v;
    if (j < 64) {
        v = neigh_h[n*64 + j];
    } else {
        const int o = j - 64;
        const int sid = seg[n];
        const float ra = neighbours[n*(long)(T*2) + (T-1)*2 + 0] - agent_traj[(long)sid*(T*2) + (T-1)*2 + 0];
        const float rbv= neighbours[n*(long)(T*2) + (T-1)*2 + 1] - agent_traj[(long)sid*(T*2) + (T-1)*2 + 1];
        v = fmaf(rW[o*2+0], ra, fmaf(rW[o*2+1], rbv, rb[o]));
    }
    x0hi[n*128 + j] = f2bf(v);
    x0lo[n*128 + j] = f2bf(v - bf_hi(v));
}

// ---------------------------------------------------------------------------
// Weight prep: frag-order bf16 hi/lo split, optional per-K scale fold.
// ---------------------------------------------------------------------------
__global__ __launch_bounds__(64) void prep_wfrag(
    const float* __restrict__ W, const float* __restrict__ sc, int K,
    unsigned short* __restrict__ Whi, unsigned short* __restrict__ Wlo)
{
    const int nKc = K >> 5;
    const int blk = blockIdx.x;
    const int ti = blk / nKc, kc = blk - ti * nKc;
    const int l = threadIdx.x;
    const int n = ti * 16 + (l & 15);
    const int k0 = kc * 32 + (l >> 4) * 8;
    const long ob = ((long)blk * 64 + l) * 8;
#pragma unroll
    for (int j = 0; j < 8; ++j) {
        float v = W[(long)n * K + k0 + j];
        if (sc) v *= sc[k0 + j];
        Whi[ob + j] = f2bf(v);
        Wlo[ob + j] = f2bf(v - bf_hi(v));
    }
}

// bias fold: b'[n] = b[n] + sum_k sh[k]*W[n,k]  (sh may be null). grid=O, blk=64
__global__ __launch_bounds__(64) void prep_bias(
    const float* __restrict__ W, const float* __restrict__ sh,
    const float* __restrict__ b, int K, float* __restrict__ bout)
{
    const int n = blockIdx.x;
    const int l = threadIdx.x;
    float s = 0.f;
    if (sh)
        for (int k = l; k < K; k += 64) s += sh[k] * W[(long)n * K + k];
#pragma unroll
    for (int m = 32; m >= 1; m >>= 1) s += __shfl_xor(s, m, 64);
    if (l == 0) bout[n] = b[n] + s;
}

// ---------------------------------------------------------------------------
// Split-activation MFMA GEMM (R13-verified plateau): XCD-aware block swizzle
// (FETCH 270->44 MB), LDS A-tile double-buffered, one __syncthreads per kc.
// launch_bounds (256,2): R10 measured (256,4) forces VGPR 104->64 + 1.8 GB
// spill; R14 measured that removing LDS staging entirely regresses (compiler
// won't pipeline naked global loads: VGPR 72, MfmaUtil 19%). Do not change.
// nKc must be EVEN. Requires gridDim.y % 8 == 0.
// Modes: Yf (fp32) | Yhi/Ylo (bf16 planes) | segp+poolmax (fused segment-max).
// Optional fused column stats into accum[2*O].
// ---------------------------------------------------------------------------
__global__ __launch_bounds__(256, 2) void gemm_split(
    const unsigned short* __restrict__ Ahi,
    const unsigned short* __restrict__ Alo,
    const unsigned short* __restrict__ Whi,
    const unsigned short* __restrict__ Wlo,
    const float* __restrict__ bias,
    float* __restrict__ Yf,
    unsigned short* __restrict__ Yhi,
    unsigned short* __restrict__ Ylo,
    float* __restrict__ accum,
    const int* __restrict__ segp,
    float* __restrict__ poolmax,
    int M, int K, int O)
{
    __shared__ unsigned short As[2][2][128 * 56];   // [buf][hi/lo]
    __shared__ int segl[128];
    const int t = threadIdx.x;
    const int lane = t & 63;
    const int w = t >> 6;
    const int wm = w & 1, wn = w >> 1;

    // XCD swizzle: flat -> (row panel, col panel)
    const int nx = gridDim.x;
    const int flat = blockIdx.y * nx + blockIdx.x;
    const int grp = flat / (8 * nx);
    const int loc = flat - grp * (8 * nx);
    const int m0 = (grp * 8 + (loc & 7)) * 128;
    const int n0 = (loc >> 3) * 128;
    const int nKc = K >> 5;   // even

    f32x4 acc[4][4];
#pragma unroll
    for (int mt = 0; mt < 4; ++mt)
#pragma unroll
    for (int nt = 0; nt < 4; ++nt) acc[mt][nt] = (f32x4)0.f;

    const long aoff = (long)(m0 + (t >> 1)) * K + (t & 1) * 16;
    const unsigned short* aph = Ahi + aoff;
    const unsigned short* apl = Alo + aoff;
    const int so = (t >> 1) * 56 + (t & 1) * 16;
    const int arow = wm * 64 + (lane & 15);
    const int acol = (lane >> 4) * 8;
    const long bt0 = (long)((n0 >> 4) + wn * 4);

    uint4 rah0, rah1, ral0, ral1;
    auto loadAreg = [&](int kc) {
        rah0 = *(const uint4*)(aph + kc * 32);
        rah1 = *(const uint4*)(aph + kc * 32 + 8);
        ral0 = *(const uint4*)(apl + kc * 32);
        ral1 = *(const uint4*)(apl + kc * 32 + 8);
    };
    auto storeAs = [&](int buf) {
        *(uint4*)&As[buf][0][so] = rah0; *(uint4*)&As[buf][0][so + 8] = rah1;
        *(uint4*)&As[buf][1][so] = ral0; *(uint4*)&As[buf][1][so + 8] = ral1;
    };
    auto loadB = [&](BFrag* bh, BFrag* bl, int kc) {
#pragma unroll
        for (int nt = 0; nt < 4; ++nt) {
            const long fb = ((bt0 + nt) * nKc + kc) * 512 + lane * 8;
            bh[nt].u = *(const uint4*)(Whi + fb);
            bl[nt].u = *(const uint4*)(Wlo + fb);
        }
    };
    auto compute = [&](int buf, BFrag* bh, BFrag* bl) {
        BFrag afh[4], afl[4];
#pragma unroll
        for (int mt = 0; mt < 4; ++mt) {
            afh[mt].u = *(const uint4*)&As[buf][0][(arow + mt * 16) * 56 + acol];
            afl[mt].u = *(const uint4*)&As[buf][1][(arow + mt * 16) * 56 + acol];
        }
#pragma unroll
        for (int nt = 0; nt < 4; ++nt)
#pragma unroll
        for (int mt = 0; mt < 4; ++mt) {
            f32x4 a = acc[mt][nt];
            a = __builtin_amdgcn_mfma_f32_16x16x32_bf16(afh[mt].v, bh[nt].v, a, 0, 0, 0);
            a = __builtin_amdgcn_mfma_f32_16x16x32_bf16(afh[mt].v, bl[nt].v, a, 0, 0, 0);
            a = __builtin_amdgcn_mfma_f32_16x16x32_bf16(afl[mt].v, bh[nt].v, a, 0, 0, 0);
            acc[mt][nt] = a;
        }
    };

    BFrag bh0[4], bl0[4], bh1[4], bl1[4];
    loadAreg(0);
    loadB(bh0, bl0, 0);
    storeAs(0);
    __syncthreads();
    for (int kc = 0; kc < nKc; kc += 2) {
        loadAreg(kc + 1);
        loadB(bh1, bl1, kc + 1);
        compute(0, bh0, bl0);
        storeAs(1);
        __syncthreads();
        if (kc + 2 < nKc) {
            loadAreg(kc + 2);
            loadB(bh0, bl0, kc + 2);
        }
        compute(1, bh1, bl1);
        if (kc + 2 < nKc) {
            storeAs(0);
            __syncthreads();
        }
    }

    if (segp) {
        __syncthreads();
        if (t < 128) segl[t] = segp[m0 + t];
        __syncthreads();
    }

    const int cn = lane & 15, cq = lane >> 4;
#pragma unroll
    for (int nt = 0; nt < 4; ++nt) {
        const int n = n0 + wn * 64 + nt * 16 + cn;
        const float bs = bias[n];
        float s = 0.f, ssq = 0.f;
#pragma unroll
        for (int mt = 0; mt < 4; ++mt) {
            const int mb = wm * 64 + mt * 16 + cq * 4;
            float vmax = 0.f; int sid = -1;
#pragma unroll
            for (int r = 0; r < 4; ++r) {
                const float v = fmaxf(acc[mt][nt][r] + bs, 0.f);
                s += v; ssq += v * v;
                if (segp) {
                    const int sr = segl[mb + r];
                    if (r == 0) { vmax = v; sid = sr; }
                    else if (sr == sid) { vmax = fmaxf(vmax, v); }
                    else {
                        if (vmax > 0.f)
                            atomicMax((int*)&poolmax[(long)sid * O + n], __float_as_int(vmax));
                        sid = sr; vmax = v;
                    }
                } else if (Yf) {
                    Yf[(long)(m0 + mb + r) * O + n] = v;
                } else {
                    const long idx = (long)(m0 + mb + r) * O + n;
                    Yhi[idx] = f2bf(v);
                    Ylo[idx] = f2bf(v - bf_hi(v));
                }
            }
            if (segp && vmax > 0.f)
                atomicMax((int*)&poolmax[(long)sid * O + n], __float_as_int(vmax));
        }
        if (accum) {
            s   += __shfl_xor(s, 16, 64);   ssq += __shfl_xor(ssq, 16, 64);
            s   += __shfl_xor(s, 32, 64);   ssq += __shfl_xor(ssq, 32, 64);
            if (cq == 0) {
                atomicAdd(&accum[n], s);
                atomicAdd(&accum[O + n], ssq);
            }
        }
    }
}

// ---------------------------------------------------------------------------
// Column sums / sumsq (fp32). grid = (O/64, chunks). Used only for t2.
// ---------------------------------------------------------------------------
__global__ __launch_bounds__(256) void colstats(
    const float* __restrict__ Y, int M, int O, int chunkRows,
    float* __restrict__ accum)
{
    const int c = blockIdx.x * 64 + (threadIdx.x & 63);
    const int rgrp = threadIdx.x >> 6;
    const int r0 = blockIdx.y * chunkRows;
    int rend = r0 + chunkRows; if (rend > M) rend = M;
    float s = 0.f, ss = 0.f;
    for (int r = r0 + rgrp; r < rend; r += 4) {
        const float v = Y[(long)r*O + c];
        s += v; ss += v*v;
    }
    __shared__ float l1[256], l2[256];
    l1[threadIdx.x] = s; l2[threadIdx.x] = ss;
    __syncthreads();
    if (threadIdx.x < 64) {
        const int c2 = blockIdx.x * 64 + threadIdx.x;
        s  = l1[threadIdx.x] + l1[threadIdx.x+64] + l1[threadIdx.x+128] + l1[threadIdx.x+192];
        ss = l2[threadIdx.x] + l2[threadIdx.x+64] + l2[threadIdx.x+128] + l2[threadIdx.x+192];
        atomicAdd(&accum[c2], s);
        atomicAdd(&accum[O + c2], ss);
    }
}

__global__ __launch_bounds__(256) void bn_finalize(
    const float* __restrict__ accum, const float* __restrict__ g,
    const float* __restrict__ be, int O, float invM,
    float* __restrict__ scale, float* __restrict__ shift)
{
    const int o = blockIdx.x * 256 + threadIdx.x;
    if (o < O) {
        const float mean = accum[o] * invM;
        const float var  = accum[O + o] * invM - mean * mean;
        const float sc   = g[o] * rsqrtf(var + EPS_BN);
        scale[o] = sc;
        shift[o] = be[o] - mean * sc;
    }
}

// ---------------------------------------------------------------------------
// d0 = concat( BN2-affine(poolmax) or 0 (empty segment), agent_h ) -> hi/lo
// ---------------------------------------------------------------------------
__global__ __launch_bounds__(256) void build_d0(
    const float* __restrict__ poolraw, const float* __restrict__ agent_h,
    const int* __restrict__ seg, int N,
    const float* __restrict__ sc2, const float* __restrict__ sh2,
    unsigned short* __restrict__ d0hi, unsigned short* __restrict__ d0lo)
{
    const int b = blockIdx.x;
    int l = 0, h = N;
    while (l < h) { const int mid = (l + h) >> 1; if (seg[mid] < b) l = mid + 1; else h = mid; }
    const bool nonempty = (l < N) && (seg[l] == b);
    for (int c = threadIdx.x; c < 1088; c += 256) {
        float v;
        if (c < 1024) {
            v = nonempty ? fmaf(sc2[c], poolraw[(long)b*1024 + c], sh2[c]) : 0.f;
        } else {
            v = agent_h[(long)b*64 + (c - 1024)];
        }
        d0hi[(long)b*1088 + c] = f2bf(v);
        d0lo[(long)b*1088 + c] = f2bf(v - bf_hi(v));
    }
}

// ---------------------------------------------------------------------------
// i2 K-split partial GEMM (fp32, O=64): grid (M/128, KS).
// ---------------------------------------------------------------------------
__global__ __launch_bounds__(256) void gemm_i2_part(
    const float* __restrict__ A,   // [M, K] fp32
    const float* __restrict__ W,   // [64, K]
    const float* __restrict__ ascale, const float* __restrict__ ashift,
    float* __restrict__ part, int M, int K, int kchunk)
{
    __shared__ float As[16][132];
    __shared__ float Bs[16][68];
    const int t = threadIdx.x;
    const int m0 = blockIdx.x * 128;
    const int ks = blockIdx.y;
    const int kbeg = ks * kchunk;
    const int kend = kbeg + kchunk;
    const int tm = (t & 15) * 8;
    const int tn = (t >> 4) * 4;
    const int ar = t >> 1;          // 0..127
    const int ac = (t & 1) * 8;     // 0 or 8
    const int br = t >> 2;          // 0..63
    const int bc = (t & 3) * 4;     // 0,4,8,12

    float acc[8][4];
#pragma unroll
    for (int i = 0; i < 8; ++i)
#pragma unroll
    for (int j = 0; j < 4; ++j) acc[i][j] = 0.f;

    for (int k0 = kbeg; k0 < kend; k0 += 16) {
        float4 a0 = *(const float4*)&A[(long)(m0+ar)*K + k0 + ac];
        float4 a1 = *(const float4*)&A[(long)(m0+ar)*K + k0 + ac + 4];
        float4 s0 = *(const float4*)&ascale[k0 + ac];
        float4 s1 = *(const float4*)&ascale[k0 + ac + 4];
        float4 h0 = *(const float4*)&ashift[k0 + ac];
        float4 h1 = *(const float4*)&ashift[k0 + ac + 4];
        a0.x = fmaf(a0.x, s0.x, h0.x); a0.y = fmaf(a0.y, s0.y, h0.y);
        a0.z = fmaf(a0.z, s0.z, h0.z); a0.w = fmaf(a0.w, s0.w, h0.w);
        a1.x = fmaf(a1.x, s1.x, h1.x); a1.y = fmaf(a1.y, s1.y, h1.y);
        a1.z = fmaf(a1.z, s1.z, h1.z); a1.w = fmaf(a1.w, s1.w, h1.w);
        float4 b0 = *(const float4*)&W[(long)br*K + k0 + bc];
        __syncthreads();
        As[ac+0][ar] = a0.x; As[ac+1][ar] = a0.y; As[ac+2][ar] = a0.z; As[ac+3][ar] = a0.w;
        As[ac+4][ar] = a1.x; As[ac+5][ar] = a1.y; As[ac+6][ar] = a1.z; As[ac+7][ar] = a1.w;
        Bs[bc+0][br] = b0.x; Bs[bc+1][br] = b0.y; Bs[bc+2][br] = b0.z; Bs[bc+3][br] = b0.w;
        __syncthreads();
#pragma unroll
        for (int kk = 0; kk < 16; ++kk) {
            float av[8], bv[4];
            *(float4*)&av[0] = *(const float4*)&As[kk][tm];
            *(float4*)&av[4] = *(const float4*)&As[kk][tm + 4];
            *(float4*)&bv[0] = *(const float4*)&Bs[kk][tn];
#pragma unroll
            for (int i = 0; i < 8; ++i)
#pragma unroll
            for (int j = 0; j < 4; ++j)
                acc[i][j] = fmaf(av[i], bv[j], acc[i][j]);
        }
    }

    float* po = part + (long)ks * M * 64;
#pragma unroll
    for (int i = 0; i < 8; ++i)
        *(float4*)&po[(long)(m0 + tm + i) * 64 + tn] = *(float4*)&acc[i][0];
}

// t2 = relu(sum_ks part + bias). grid = M*64/256.
__global__ __launch_bounds__(256) void i2_finish(
    const float* __restrict__ part, const float* __restrict__ bias,
    int M, int KS, float* __restrict__ t2)
{
    const long idx = (long)blockIdx.x * 256 + threadIdx.x;
    if (idx < (long)M * 64) {
        float s = 0.f;
        for (int ks = 0; ks < KS; ++ks) s += part[(long)ks * M * 64 + idx];
        t2[idx] = fmaxf(s + bias[idx & 63], 0.f);
    }
}

// decoder weights: Wc = dW_ih + dW_hh, bc = db_ih + db_hh
__global__ __launch_bounds__(256) void prep_dec(
    const float* __restrict__ dW_ih, const float* __restrict__ dW_hh,
    const float* __restrict__ db_ih, const float* __restrict__ db_hh,
    float* __restrict__ Wc, float* __restrict__ bc)
{
    const int idx = blockIdx.x * 256 + threadIdx.x;
    if (idx < 256*64) Wc[idx] = dW_ih[idx] + dW_hh[idx];
    else if (idx < 256*64 + 256) bc[idx - 256*64] = db_ih[idx - 256*64] + db_hh[idx - 256*64];
}

// ---------------------------------------------------------------------------
// Autoregressive decoder: 30 LSTMCell steps (input == h), fused prediction.
// ---------------------------------------------------------------------------
__global__ __launch_bounds__(256) void decoder_kernel(
    const float* __restrict__ t2, const float* __restrict__ sc4,
    const float* __restrict__ sh4, const float* __restrict__ agent_c,
    const float* __restrict__ Wc, const float* __restrict__ bc,
    const float* __restrict__ pW, const float* __restrict__ pb,
    float* __restrict__ pred /*[B,30,2]*/)
{
    __shared__ float h_lds[2][64];
    __shared__ float zg_lds[2][64];
    __shared__ float zo_lds[2][64];
    const int t = threadIdx.x;
    const int lane = t & 63;
    const int wave = t >> 6;
    const int s = wave >> 1;
    const int role = wave & 1;
    const long seq = (long)blockIdx.x * 2 + s;

    const int r0 = role * 128 + lane;
    const int r1 = r0 + 64;
    float w0[64], w1[64];
#pragma unroll
    for (int k = 0; k < 64; k += 4) {
        float4 va = *(const float4*)&Wc[r0 * 64 + k];
        w0[k] = va.x; w0[k+1] = va.y; w0[k+2] = va.z; w0[k+3] = va.w;
        float4 vb = *(const float4*)&Wc[r1 * 64 + k];
        w1[k] = vb.x; w1[k+1] = vb.y; w1[k+2] = vb.z; w1[k+3] = vb.w;
    }
    const float bias0 = bc[r0];
    const float bias1 = bc[r1];
    const float pw0 = pW[lane], pw1 = pW[64 + lane];
    const float pb0 = pb[0], pb1 = pb[1];

    float c = agent_c[seq*64 + lane];
    if (role == 0)
        h_lds[s][lane] = fmaf(sc4[lane], t2[seq*64 + lane], sh4[lane]);
    __syncthreads();
    float hv = h_lds[s][lane];

    for (int step = 0; step < 30; ++step) {
        float z0 = bias0, z1 = bias1;
#pragma unroll
        for (int k = 0; k < 64; ++k) {
            float hk = __int_as_float(__builtin_amdgcn_readlane(__float_as_int(hv), k));
            z0 = fmaf(hk, w0[k], z0);
            z1 = fmaf(hk, w1[k], z1);
        }
        if (role == 1) { zg_lds[s][lane] = z0; zo_lds[s][lane] = z1; }
        __syncthreads();
        if (role == 0) {
            const float ig = sigmoid_f(z0);
            const float fg = sigmoid_f(z1);
            const float gg = tanh_f(zg_lds[s][lane]);
            const float og = sigmoid_f(zo_lds[s][lane]);
            c = fmaf(fg, c, ig * gg);
            h_lds[s][lane] = og * tanh_f(c);
        }
        __syncthreads();
        hv = h_lds[s][lane];
        if (role == 0) {
            float p0 = hv * pw0;
            float p1 = hv * pw1;
#pragma unroll
            for (int m = 32; m >= 1; m >>= 1) {
                p0 += __shfl_xor(p0, m, 64);
                p1 += __shfl_xor(p1, m, 64);
            }
            if (lane == 0) {
                pred[seq*60 + step*2 + 0] = p0 + pb0;
                pred[seq*60 + step*2 + 1] = p1 + pb1;
            }
        }
    }
}

// ---------------------------------------------------------------------------
extern "C" void kernel_launch(void* const* d_in, const int* in_sizes, int n_in,
                              void* d_out, int out_size, void* d_ws, size_t ws_size,
                              hipStream_t stream)
{
    const float* agent_traj = (const float*)d_in[0];
    const float* neighbours = (const float*)d_in[1];
    const float* aW_ih = (const float*)d_in[2];
    const float* aW_hh = (const float*)d_in[3];
    const float* ab_ih = (const float*)d_in[4];
    const float* ab_hh = (const float*)d_in[5];
    const float* nW_ih = (const float*)d_in[6];
    const float* nW_hh = (const float*)d_in[7];
    const float* nb_ih = (const float*)d_in[8];
    const float* nb_hh = (const float*)d_in[9];
    const float* dW_ih = (const float*)d_in[10];
    const float* dW_hh = (const float*)d_in[11];
    const float* db_ih = (const float*)d_in[12];
    const float* db_hh = (const float*)d_in[13];
    const float* pW = (const float*)d_in[14];
    const float* pb = (const float*)d_in[15];
    const float* rW = (const float*)d_in[16];
    const float* rb = (const float*)d_in[17];
    const float* m1W = (const float*)d_in[18];
    const float* m1b = (const float*)d_in[19];
    const float* g1  = (const float*)d_in[20];
    const float* be1 = (const float*)d_in[21];
    const float* m2W = (const float*)d_in[22];
    const float* m2b = (const float*)d_in[23];
    const float* g2  = (const float*)d_in[24];
    const float* be2 = (const float*)d_in[25];
    const float* i1W = (const float*)d_in[26];
    const float* i1b = (const float*)d_in[27];
    const float* ig1 = (const float*)d_in[28];
    const float* ib1 = (const float*)d_in[29];
    const float* i2W = (const float*)d_in[30];
    const float* i2b = (const float*)d_in[31];
    const float* ig2 = (const float*)d_in[32];
    const float* ib2 = (const float*)d_in[33];
    const int*   seg = (const int*)d_in[34];
    float* pred = (float*)d_out;

    const int B = 2048, T = 20, N = 32768;

    char* p = (char*)d_ws;
    auto alloc = [&](size_t bytes) -> char* {
        char* r = p; p += (bytes + 255) & ~(size_t)255; return r;
    };
    float* agent_h = (float*)alloc((size_t)B*64*4);
    float* agent_c = (float*)alloc((size_t)B*64*4);
    char* neigh_region = alloc((size_t)N*64*4);          // neigh_h, later t1 (fp32 B*1024)
    unsigned short* x0hi = (unsigned short*)alloc((size_t)N*128*2);
    unsigned short* x0lo = (unsigned short*)alloc((size_t)N*128*2);
    char* y1hi_region  = alloc((size_t)N*512*2);         // y1hi, later d0hi/d0lo/t2
    unsigned short* y1lo = (unsigned short*)alloc((size_t)N*512*2);
    float* poolraw = (float*)alloc((size_t)B*1024*4);    // 8 MB, zero-init
    float* accAll = (float*)alloc((size_t)(1024+2048+2048+128)*4);
    float* acc1 = accAll;            // 2*512
    float* acc2 = accAll + 1024;     // 2*1024
    float* acc3 = accAll + 3072;     // 2*1024
    float* acc4 = accAll + 5120;     // 2*64
    float* sc1 = (float*)alloc(512*4);  float* sh1 = (float*)alloc(512*4);
    float* sc2 = (float*)alloc(1024*4); float* sh2 = (float*)alloc(1024*4);
    float* sc3 = (float*)alloc(1024*4); float* sh3 = (float*)alloc(1024*4);
    float* sc4 = (float*)alloc(64*4);   float* sh4 = (float*)alloc(64*4);
    float* Wc = (float*)alloc(256*64*4);
    float* bc = (float*)alloc(256*4);
    unsigned short* W1hi = (unsigned short*)alloc((size_t)512*128*2);
    unsigned short* W1lo = (unsigned short*)alloc((size_t)512*128*2);
    unsigned short* W2hi = (unsigned short*)alloc((size_t)1024*512*2);
    unsigned short* W2lo = (unsigned short*)alloc((size_t)1024*512*2);
    unsigned short* Wi1hi = (unsigned short*)alloc((size_t)1024*1088*2);
    unsigned short* Wi1lo = (unsigned short*)alloc((size_t)1024*1088*2);
    float* b1f = (float*)alloc(512*4);
    float* b2f = (float*)alloc(1024*4);
    float* bi1f = (float*)alloc(1024*4);
    float* i2part = (float*)alloc((size_t)8*B*64*4);     // 4 MB partials

    // aliases (lifetimes disjoint, stream-ordered)
    float* neigh_h = (float*)neigh_region;
    float* t1      = (float*)neigh_region;       // after build_x0
    unsigned short* y1hi = (unsigned short*)y1hi_region;
    unsigned short* d0hi = (unsigned short*)y1hi_region;          // after MLP2
    unsigned short* d0lo = d0hi + (size_t)B*1088;
    float* t2 = (float*)(y1hi_region + (size_t)2*B*1088*2);

    hipMemsetAsync(accAll, 0, (1024+2048+2048+128)*sizeof(float), stream);
    hipMemsetAsync(poolraw, 0, (size_t)B*1024*4, stream);

    // weight preps that need no BN stats
    prep_wfrag<<<(512/16)*(128/32), 64, 0, stream>>>(m1W, nullptr, 128, W1hi, W1lo);
    prep_bias<<<512, 64, 0, stream>>>(m1W, nullptr, m1b, 128, b1f);
    prep_wfrag<<<(1024/16)*(1088/32), 64, 0, stream>>>(i1W, nullptr, 1088, Wi1hi, Wi1lo);
    prep_bias<<<1024, 64, 0, stream>>>(i1W, nullptr, i1b, 1088, bi1f);
    prep_dec<<<65, 256, 0, stream>>>(dW_ih, dW_hh, db_ih, db_hh, Wc, bc);

    // merged agent+neighbour LSTM: one dispatch, 128 + 2048 blocks
    lstm_mfma<<<B/16 + N/16, 256, 0, stream>>>(
        agent_traj, aW_ih, aW_hh, ab_ih, ab_hh, agent_h, agent_c,
        neighbours, nW_ih, nW_hh, nb_ih, nb_hh, neigh_h,
        B/16, T);
    build_x0<<<N/2, 256, 0, stream>>>(neigh_h, neighbours, agent_traj, seg, rW, rb,
                                      x0hi, x0lo, T);

    // MLP1 (fused colstats -> acc1)
    gemm_split<<<dim3(512/128, N/128), 256, 0, stream>>>(
        x0hi, x0lo, W1hi, W1lo, b1f, nullptr, y1hi, y1lo, acc1,
        nullptr, nullptr, N, 128, 512);
    bn_finalize<<<2, 256, 0, stream>>>(acc1, g1, be1, 512, 1.0f/N, sc1, sh1);

    // fold BN1 into W2
    prep_wfrag<<<(1024/16)*(512/32), 64, 0, stream>>>(m2W, sc1, 512, W2hi, W2lo);
    prep_bias<<<1024, 64, 0, stream>>>(m2W, sh1, m2b, 512, b2f);

    // MLP2 (fused colstats -> acc2, fused segment-max -> poolraw; y2 never hits HBM)
    gemm_split<<<dim3(1024/128, N/128), 256, 0, stream>>>(
        y1hi, y1lo, W2hi, W2lo, b2f, nullptr, nullptr, nullptr, acc2,
        seg, poolraw, N, 512, 1024);
    bn_finalize<<<4, 256, 0, stream>>>(acc2, g2, be2, 1024, 1.0f/N, sc2, sh2);

    build_d0<<<B, 256, 0, stream>>>(poolraw, agent_h, seg, N, sc2, sh2, d0hi, d0lo);

    // i1 (fused colstats -> acc3)
    gemm_split<<<dim3(1024/128, B/128), 256, 0, stream>>>(
        d0hi, d0lo, Wi1hi, Wi1lo, bi1f, t1, nullptr, nullptr, acc3,
        nullptr, nullptr, B, 1088, 1024);
    bn_finalize<<<4, 256, 0, stream>>>(acc3, ig1, ib1, 1024, 1.0f/B, sc3, sh3);

    // i2: K-split partials + finish
    gemm_i2_part<<<dim3(B/128, 8), 256, 0, stream>>>(t1, i2W, sc3, sh3, i2part,
                                                     B, 1024, 128);
    i2_finish<<<(B*64)/256, 256, 0, stream>>>(i2part, i2b, B, 8, t2);
    colstats<<<dim3(1, 8), 256, 0, stream>>>(t2, B, 64, 256, acc4);
    bn_finalize<<<1, 256, 0, stream>>>(acc4, ig2, ib2, 64, 1.0f/B, sc4, sh4);

    decoder_kernel<<<B/2, 256, 0, stream>>>(t2, sc4, sh4, agent_c, Wc, bc, pW, pb, pred);
}